// Round 12
// baseline (976.331 us; speedup 1.0000x reference)
//
#include <hip/hip_runtime.h>
#include <stdint.h>
#include <stddef.h>

// ---------------------------------------------------------------------------
// DiffusionActionHead: fully fused 10-step DDPM sampler, bf16 MFMA.
//   B=32768, H=256, A=4, 10 inference steps.
//   1. wprep_kernel  : repack 10 weight matrices + final_w tile -> bf16 frags
//   2. prep_kernel   : per-step temb-derived col-vectors tw1/tskip + scalars
//   3. noise_kernel  : JAX threefry2x32, PARTITIONABLE counter scheme
//   4. cond_kernel   : cond = features @ cond_w + cond_b  (bf16 out)
//   5. fused_kernel  : 10 steps x 9 K=256 GEMMs per 32-row tile.
//      ROUND 11 RESUBMIT (r11 bench was an infra failure -- GPU acquisition
//      timeout; hypothesis untested. Source identical to r11):
//      post-mortem r10: occupancy hypothesis DEAD -- 42.8% occ with 2
//      co-resident blocks gave dur identical to 23.5% (799 vs 794).
//      ~790us is occupancy-invariant => bound by per-wave VALU+LDS+barrier
//      chain. Only work REMOVAL moves it:
//        - double-buffered lact0/lact1 -> 9 barriers/step (r5's proven win;
//          LDS 52.7KB, 2 blocks = 105KB <= 142KB proven-resident).
//        - pred via MFMA: 11th weight tile = final_w (256x4 -> bf16 frag,
//          cols 0..3 live in ntiles 0,1 at l16<2). Replaces per-step
//          256 ds_read_b32 + 256 fmaf per thread (2 waves, 75% lanes idle)
//          with 32 MFMA + 16 ds_read on wave 0. lfw buffer deleted.
//        - keep: FTILE=32 + 2 blocks/CU (43% occ), KP=272, dual GEMM,
//          packed f32x2 epilogues, __launch_bounds__(512,2).
// ---------------------------------------------------------------------------

typedef __bf16 bf16_t;
typedef __bf16 bf16x8 __attribute__((ext_vector_type(8)));
typedef __bf16 bf16x4 __attribute__((ext_vector_type(4)));
typedef __bf16 bf16x2 __attribute__((ext_vector_type(2)));
typedef float  f32x4  __attribute__((ext_vector_type(4)));
typedef float  f32x2  __attribute__((ext_vector_type(2)));

constexpr int KP    = 272;   // LDS row stride in bf16 elems (256 + 16 pad)
constexpr int MTILE = 64;    // rows per cond_kernel workgroup
constexpr int FTILE = 32;    // rows per fused_kernel workgroup

// ---------------- packed f32x2 helpers -------------------------------------
__device__ __forceinline__ f32x2 bc2(float v) { return f32x2{v, v}; }
__device__ __forceinline__ f32x2 fma2(f32x2 a, f32x2 b, f32x2 c) {
#if __has_builtin(__builtin_elementwise_fma)
  return __builtin_elementwise_fma(a, b, c);
#else
  return f32x2{fmaf(a[0], b[0], c[0]), fmaf(a[1], b[1], c[1])};
#endif
}
__device__ __forceinline__ f32x2 abs2(f32x2 x) {
#if __has_builtin(__builtin_elementwise_abs)
  return __builtin_elementwise_abs(x);
#else
  return f32x2{fabsf(x[0]), fabsf(x[1])};
#endif
}

// ---------------- exact-erf GELU (A&S 7.1.26), scalar and packed ------------
__device__ __forceinline__ float gelu_f(float x) {
  float z  = 0.70710678f * x;
  float az = fabsf(z);
  float t  = __builtin_amdgcn_rcpf(fmaf(0.3275911f, az, 1.0f));
  float e  = __expf(-az * az);
  float p  = fmaf(1.061405429f, t, -1.453152027f);
  p = fmaf(p, t, 1.421413741f);
  p = fmaf(p, t, -0.284496736f);
  p = fmaf(p, t, 0.254829592f);
  float er = fmaf(-(p * t), e, 1.0f);   // erf(|z|)
  er = copysignf(er, z);
  return 0.5f * x * (1.0f + er);
}
// per-half op sequence identical to gelu_f (fma2==fmaf per lane)
__device__ __forceinline__ f32x2 gelu2(f32x2 x) {
  f32x2 z  = bc2(0.70710678f) * x;
  f32x2 az = abs2(z);
  f32x2 d  = fma2(bc2(0.3275911f), az, bc2(1.0f));
  f32x2 t; t[0] = __builtin_amdgcn_rcpf(d[0]); t[1] = __builtin_amdgcn_rcpf(d[1]);
  f32x2 naz = -az * az;
  f32x2 e; e[0] = __expf(naz[0]); e[1] = __expf(naz[1]);
  f32x2 p  = fma2(bc2(1.061405429f), t, bc2(-1.453152027f));
  p = fma2(p, t, bc2(1.421413741f));
  p = fma2(p, t, bc2(-0.284496736f));
  p = fma2(p, t, bc2(0.254829592f));
  f32x2 q  = p * t;
  f32x2 er = fma2(-q, e, bc2(1.0f));
  er[0] = copysignf(er[0], z[0]);
  er[1] = copysignf(er[1], z[1]);
  return (bc2(0.5f) * x) * (bc2(1.0f) + er);
}

// ---------------- JAX threefry2x32 (20 rounds) ------------------------------
#define TFR(a) x0 += x1; x1 = (x1 << (a)) | (x1 >> (32 - (a))); x1 ^= x0;
__device__ __forceinline__ void tf2(uint32_t k0, uint32_t k1,
                                    uint32_t x0, uint32_t x1,
                                    uint32_t& o0, uint32_t& o1) {
  uint32_t k2 = k0 ^ k1 ^ 0x1BD11BDAu;
  x0 += k0; x1 += k1;
  TFR(13) TFR(15) TFR(26) TFR(6)
  x0 += k1; x1 += k2 + 1u;
  TFR(17) TFR(29) TFR(16) TFR(24)
  x0 += k2; x1 += k0 + 2u;
  TFR(13) TFR(15) TFR(26) TFR(6)
  x0 += k0; x1 += k1 + 3u;
  TFR(17) TFR(29) TFR(16) TFR(24)
  x0 += k1; x1 += k2 + 4u;
  TFR(13) TFR(15) TFR(26) TFR(6)
  x0 += k2; x1 += k0 + 5u;
  o0 = x0; o1 = x1;
}
#undef TFR

// uniform bits -> N(0,1) exactly like jax.random.normal (XLA erfinv poly)
__device__ __forceinline__ float nrm_from_bits(uint32_t bits) {
  float f = __uint_as_float((bits >> 9) | 0x3f800000u) - 1.0f;  // [0,1)
  const float lo = -0.99999994f;                                 // nextafter(-1,0)
  float u = fmaxf(lo, __fadd_rn(__fmul_rn(f, 2.0f), lo));        // (hi-lo)==2.0f in f32
  float w = -log1pf(-__fmul_rn(u, u));
  float p;
  if (w < 5.0f) {
    float ww = w - 2.5f;
    p = 2.81022636e-08f;
    p = fmaf(p, ww, 3.43273939e-07f);
    p = fmaf(p, ww, -3.5233877e-06f);
    p = fmaf(p, ww, -4.39150654e-06f);
    p = fmaf(p, ww, 0.00021858087f);
    p = fmaf(p, ww, -0.00125372503f);
    p = fmaf(p, ww, -0.00417768164f);
    p = fmaf(p, ww, 0.246640727f);
    p = fmaf(p, ww, 1.50140941f);
  } else {
    float ww = sqrtf(w) - 3.0f;
    p = -0.000200214257f;
    p = fmaf(p, ww, 0.000100950558f);
    p = fmaf(p, ww, 0.00134934322f);
    p = fmaf(p, ww, -0.00367342844f);
    p = fmaf(p, ww, 0.00573950773f);
    p = fmaf(p, ww, -0.0076224613f);
    p = fmaf(p, ww, 0.00943887047f);
    p = fmaf(p, ww, 1.00167406f);
    p = fmaf(p, ww, 2.83297682f);
  }
  return 1.41421354f * (p * u);   // sqrt(2) * erfinv(u)
}

// ---------------- 64x64 MFMA tile (4 ntiles/wave, cond_kernel) -------------
__device__ __forceinline__ void mm_tile(const bf16_t* __restrict__ A,
                                        const bf16_t* __restrict__ Wp,
                                        f32x4 acc[16]) {
  #pragma unroll
  for (int i = 0; i < 16; ++i) acc[i] = f32x4{0.f, 0.f, 0.f, 0.f};
  #pragma unroll 2
  for (int kc = 0; kc < 8; ++kc) {
    bf16x8 a[4], b[4];
    #pragma unroll
    for (int rt = 0; rt < 4; ++rt)
      a[rt] = *(const bf16x8*)(A + rt * 16 * KP + kc * 32);
    #pragma unroll
    for (int ct = 0; ct < 4; ++ct)
      b[ct] = *(const bf16x8*)(Wp + ct * 4096 + kc * 512);
    #pragma unroll
    for (int rt = 0; rt < 4; ++rt)
      #pragma unroll
      for (int ct = 0; ct < 4; ++ct)
        acc[rt * 4 + ct] =
            __builtin_amdgcn_mfma_f32_16x16x32_bf16(a[rt], b[ct], acc[rt * 4 + ct], 0, 0, 0);
  }
}

// ---------------- 32x32 MFMA tile (2rt x 2ct, fused_kernel) ----------------
// A: row-major LDS, stride KP, pre-offset by l16*KP + quad*8 (rows 0..31).
// Wp: pre-offset (tile base) + lane*8; b[ct] at ct*4096 + kc*512.
__device__ __forceinline__ void mm_tile2(const bf16_t* __restrict__ A,
                                         const bf16_t* __restrict__ Wp,
                                         f32x4 acc[4]) {
  #pragma unroll
  for (int i = 0; i < 4; ++i) acc[i] = f32x4{0.f, 0.f, 0.f, 0.f};
  #pragma unroll 2
  for (int kc = 0; kc < 8; ++kc) {
    bf16x8 a[2], b[2];
    #pragma unroll
    for (int rt = 0; rt < 2; ++rt)
      a[rt] = *(const bf16x8*)(A + rt * 16 * KP + kc * 32);
    #pragma unroll
    for (int ct = 0; ct < 2; ++ct)
      b[ct] = *(const bf16x8*)(Wp + ct * 4096 + kc * 512);
    #pragma unroll
    for (int rt = 0; rt < 2; ++rt)
      #pragma unroll
      for (int ct = 0; ct < 2; ++ct)
        acc[rt * 2 + ct] =
            __builtin_amdgcn_mfma_f32_16x16x32_bf16(a[rt], b[ct], acc[rt * 2 + ct], 0, 0, 0);
  }
}

// Dual: one A pass (lcond) feeds TWO B's -> skip (acc1) + y1 (acc2)
__device__ __forceinline__ void mm_tile2_dual(const bf16_t* __restrict__ A,
                                              const bf16_t* __restrict__ W1,
                                              const bf16_t* __restrict__ W2,
                                              f32x4 acc1[4], f32x4 acc2[4]) {
  #pragma unroll
  for (int i = 0; i < 4; ++i) {
    acc1[i] = f32x4{0.f, 0.f, 0.f, 0.f};
    acc2[i] = f32x4{0.f, 0.f, 0.f, 0.f};
  }
  #pragma unroll 2
  for (int kc = 0; kc < 8; ++kc) {
    bf16x8 a[2];
    #pragma unroll
    for (int rt = 0; rt < 2; ++rt)
      a[rt] = *(const bf16x8*)(A + rt * 16 * KP + kc * 32);
    #pragma unroll
    for (int ct = 0; ct < 2; ++ct) {
      bf16x8 b = *(const bf16x8*)(W1 + ct * 4096 + kc * 512);
      #pragma unroll
      for (int rt = 0; rt < 2; ++rt)
        acc1[rt * 2 + ct] =
            __builtin_amdgcn_mfma_f32_16x16x32_bf16(a[rt], b, acc1[rt * 2 + ct], 0, 0, 0);
    }
    #pragma unroll
    for (int ct = 0; ct < 2; ++ct) {
      bf16x8 b = *(const bf16x8*)(W2 + ct * 4096 + kc * 512);
      #pragma unroll
      for (int rt = 0; rt < 2; ++rt)
        acc2[rt * 2 + ct] =
            __builtin_amdgcn_mfma_f32_16x16x32_bf16(a[rt], b, acc2[rt * 2 + ct], 0, 0, 0);
    }
  }
}

// ---------------- kernel 1: weight repack ----------------------------------
// dst element e = [m][nt][kc][lane][j]; value = src_m[k*256 + n],
// COLUMN REMAP: n = (nt>>1)*32 + (lane&15)*2 + (nt&1)
// m==10 (compact, 8192 elems, ntiles 0..1): final_w 256x4 zero-padded;
//   col n = l16*2 + nt < 4 only for l16 < 2.
__global__ void wprep_kernel(const float* __restrict__ condw,
                             const float* __restrict__ w1,
                             const float* __restrict__ skw,
                             const float* __restrict__ w2,
                             const float* __restrict__ bw1,
                             const float* __restrict__ bw2,
                             const float* __restrict__ fw,
                             bf16_t* __restrict__ wts) {
  int e = blockIdx.x * 256 + threadIdx.x;
  int m = e >> 16;
  int r = e & 65535;
  int nt = r >> 12, kc = (r >> 9) & 7, lane = (r >> 3) & 63, j = r & 7;
  int n = (nt >> 1) * 32 + (lane & 15) * 2 + (nt & 1);
  int k = kc * 32 + (lane >> 4) * 8 + j;
  if (m == 10) {                               // compact final_w tile
    wts[e] = (n < 4) ? (bf16_t)fw[k * 4 + n] : (bf16_t)0.f;
    return;
  }
  const float* src;
  if      (m == 0) src = condw;
  else if (m == 1) src = w1;                    // blk0_w1 rows 0..255 (cond part)
  else if (m == 2) src = skw;                   // blk0_skip_w rows 0..255
  else if (m == 3) src = w2;                    // blk0_w2
  else if (m <= 6) src = bw1 + (m - 4) * 65536; // blks_w1[i]
  else             src = bw2 + (m - 7) * 65536; // blks_w2[i]
  wts[e] = (bf16_t)src[k * 256 + n];
}

// ---------------- kernel 2: per-step vectors + scalars ---------------------
__global__ void prep_kernel(const float* __restrict__ time_w,
                            const float* __restrict__ time_b,
                            const float* __restrict__ w1,
                            const float* __restrict__ b1,
                            const float* __restrict__ skw,
                            const float* __restrict__ skb,
                            float* __restrict__ tvecs,
                            float* __restrict__ stepsc) {
  int s = blockIdx.x;          // 0..9, t = 90 - 10*s
  int j = threadIdx.x;         // 0..255
  int t = 90 - s * 10;
  float tval = (float)t;
  __shared__ float emb[256];
  __shared__ float temb[256];
  if (j < 128) {
    float freq = expf((float)j * -0.07252236513366287f);  // -ln(1e4)/127
    float e = tval * freq;
    emb[j] = sinf(e);
    emb[j + 128] = cosf(e);
  }
  __syncthreads();
  float a = time_b[j];
  for (int k = 0; k < 256; ++k) a = fmaf(emb[k], time_w[k * 256 + j], a);
  temb[j] = gelu_f(a);
  __syncthreads();
  float v1 = b1[j], v2 = skb[j];
  for (int k = 0; k < 256; ++k) {
    float tk = temb[k];
    v1 = fmaf(tk, w1[(256 + k) * 256 + j], v1);    // blk0_w1 rows 256..511
    v2 = fmaf(tk, skw[(256 + k) * 256 + j], v2);   // blk0_skip_w rows 256..511
  }
  tvecs[s * 512 + j] = v1;         // tw1 (includes b1)
  tvecs[s * 512 + 256 + j] = v2;   // tskip (includes skip_b)
  if (j == 0) {
    float step = (0.02f - 1e-4f) / 99.0f;
    float acp = 1.0f, beta = 0.0f;
    for (int i = 0; i <= t; ++i) {
      beta = fmaf((float)i, step, 1e-4f);
      acp *= (1.0f - beta);
    }
    stepsc[s * 4 + 0] = 1.0f / sqrtf(1.0f - beta);   // 1/sqrt(alpha)
    stepsc[s * 4 + 1] = beta / sqrtf(1.0f - acp);    // b/sqrt(1-acp)
    stepsc[s * 4 + 2] = (t > 0) ? sqrtf(beta) : 0.0f;
    stepsc[s * 4 + 3] = 0.0f;
  }
}

// ---------------- kernel 3: x0 + noises via PARTITIONABLE threefry ---------
__global__ void noise_kernel(float* __restrict__ xout, float* __restrict__ nout, int nb) {
  int gid = blockIdx.x * 256 + threadIdx.x;
  int nx = nb * 4;     // 131072 x0 elements
  int nn = nb * 40;    // 1310720 noise elements
  uint32_t k0, k1, o0, o1;
  if (gid < nx) {
    tf2(0u, 42u, 0u, 999u, k0, k1);                 // fold_in(key(42), 999)
    tf2(k0, k1, 0u, (uint32_t)gid, o0, o1);
    xout[gid] = nrm_from_bits(o0 ^ o1);
  } else if (gid < nx + nn) {
    int i = gid - nx;
    tf2(0u, 42u, 0u, 7u, k0, k1);                   // fold_in(key(42), 7)
    tf2(k0, k1, 0u, (uint32_t)i, o0, o1);
    nout[i] = nrm_from_bits(o0 ^ o1);
  }
}

// ---------------- kernel 4: cond = features @ cond_w + cond_b --------------
__global__ __launch_bounds__(256, 2) void cond_kernel(
    const float* __restrict__ feat, const bf16_t* __restrict__ wts,
    const float* __restrict__ condb, bf16_t* __restrict__ condg) {
  __shared__ __align__(16) bf16_t la[MTILE * KP];
  const int tid = threadIdx.x;
  const int wave = tid >> 6, lane = tid & 63, quad = lane >> 4, l16 = lane & 15;
  const int rowbase = blockIdx.x * MTILE;
  for (int it = 0; it < 16; ++it) {
    int e = (it * 256 + tid) * 4;
    int rr = e >> 8, c = e & 255;
    f32x4 v = *(const f32x4*)(feat + (size_t)(rowbase + rr) * 256 + c);
    bf16x4 bv;
    bv[0] = (bf16_t)v[0]; bv[1] = (bf16_t)v[1];
    bv[2] = (bf16_t)v[2]; bv[3] = (bf16_t)v[3];
    *(bf16x4*)(la + rr * KP + c) = bv;
  }
  __syncthreads();
  f32x4 acc[16];
  mm_tile(la + l16 * KP + quad * 8, wts + wave * 16384 + lane * 8, acc);
  const int c0 = wave * 64 + l16 * 2;            // ct 0,1 -> c0, ct 2,3 -> c0+32
  f32x2 b0 = *(const f32x2*)(condb + c0);
  f32x2 b1 = *(const f32x2*)(condb + c0 + 32);
  #pragma unroll
  for (int rt = 0; rt < 4; ++rt)
    #pragma unroll
    for (int r = 0; r < 4; ++r) {
      int row = rt * 16 + quad * 4 + r;
      bf16x2 p0, p1;
      p0[0] = (bf16_t)(acc[rt * 4 + 0][r] + b0[0]);
      p0[1] = (bf16_t)(acc[rt * 4 + 1][r] + b0[1]);
      p1[0] = (bf16_t)(acc[rt * 4 + 2][r] + b1[0]);
      p1[1] = (bf16_t)(acc[rt * 4 + 3][r] + b1[1]);
      *(bf16x2*)(condg + (size_t)(rowbase + row) * 256 + c0) = p0;
      *(bf16x2*)(condg + (size_t)(rowbase + row) * 256 + c0 + 32) = p1;
    }
}

// ---------------- kernel 5: fused 10-step sampler (512 thr / 8 waves) ------
// FTILE=32, double-buffered lact (9 barriers/step), pred via MFMA (wave 0).
// LDS 52.7KB -> 2 blocks/CU co-resident.
__global__ __launch_bounds__(512, 2) void fused_kernel(
    const bf16_t* __restrict__ condg, const bf16_t* __restrict__ wts,
    const float* __restrict__ tvecs, const float* __restrict__ stepsc,
    const float* __restrict__ x0w, const float* __restrict__ noises,
    const float* __restrict__ w1bot, const float* __restrict__ skipbot,
    const float* __restrict__ b2v, const float* __restrict__ blksb1,
    const float* __restrict__ blksb2,
    const float* __restrict__ finalb, float* __restrict__ out, int nb) {
  __shared__ __align__(16) bf16_t lcond[FTILE * KP];
  __shared__ __align__(16) bf16_t lact0[FTILE * KP];
  __shared__ __align__(16) bf16_t lact1[FTILE * KP];
  __shared__ __align__(16) float  lx[FTILE * 4];
  const int tid = threadIdx.x;
  const int wave = tid >> 6, lane = tid & 63, quad = lane >> 4, l16 = lane & 15;
  const int rowbase = blockIdx.x * FTILE;

  // stage cond tile (persists all 10 steps) + x0
  {
    int rr = tid >> 4, c = (tid & 15) * 16;      // 32 rows x 256 cols
    const bf16_t* src = condg + (size_t)(rowbase + rr) * 256 + c;
    bf16_t* dst = lcond + rr * KP + c;
    *(bf16x8*)(dst)     = *(const bf16x8*)(src);
    *(bf16x8*)(dst + 8) = *(const bf16x8*)(src + 8);
  }
  if (tid < 128) lx[tid] = x0w[rowbase * 4 + tid];
  __syncthreads();

  const bf16_t* Acond = lcond + l16 * KP + quad * 8;
  const bf16_t* A0    = lact0 + l16 * KP + quad * 8;
  const bf16_t* A1    = lact1 + l16 * KP + quad * 8;
  const int colw = wave * 32 + l16 * 2;          // 2 consecutive cols/lane
  const int wlane = wave * 8192 + lane * 8;
  f32x4 resid[4], work[4];

  // pack lane's 2 consecutive cols -> one ds_write_b32 per (rt,r)
  auto write_act = [&](bf16_t* dst) {
    #pragma unroll
    for (int rt = 0; rt < 2; ++rt)
      #pragma unroll
      for (int r = 0; r < 4; ++r) {
        bf16x2 pv;
        pv[0] = (bf16_t)work[rt * 2 + 0][r];
        pv[1] = (bf16_t)work[rt * 2 + 1][r];
        *(bf16x2*)(dst + (rt * 16 + quad * 4 + r) * KP + colw) = pv;
      }
  };
  // merged K=516-factorized epilogue: skip (resid, no gelu) + y1 (work, gelu)
  auto epi_bot_dual = [&](const float* tvsk, const float* botsk,
                          const float* tvw, const float* botw) {
    f32x2 tcs = *(const f32x2*)(tvsk + colw);
    f32x2 ss0 = *(const f32x2*)(botsk + colw);
    f32x2 ss1 = *(const f32x2*)(botsk + 256 + colw);
    f32x2 ss2 = *(const f32x2*)(botsk + 512 + colw);
    f32x2 ss3 = *(const f32x2*)(botsk + 768 + colw);
    f32x2 tcw = *(const f32x2*)(tvw + colw);
    f32x2 sw0 = *(const f32x2*)(botw + colw);
    f32x2 sw1 = *(const f32x2*)(botw + 256 + colw);
    f32x2 sw2 = *(const f32x2*)(botw + 512 + colw);
    f32x2 sw3 = *(const f32x2*)(botw + 768 + colw);
    #pragma unroll
    for (int rt = 0; rt < 2; ++rt)
      #pragma unroll
      for (int r = 0; r < 4; ++r) {
        f32x4 xv = *(const f32x4*)(lx + (rt * 16 + quad * 4 + r) * 4);
        f32x2 vs = f32x2{resid[rt * 2][r], resid[rt * 2 + 1][r]} + tcs;
        vs = fma2(bc2(xv[0]), ss0, vs);
        vs = fma2(bc2(xv[1]), ss1, vs);
        vs = fma2(bc2(xv[2]), ss2, vs);
        vs = fma2(bc2(xv[3]), ss3, vs);
        resid[rt * 2][r] = vs[0]; resid[rt * 2 + 1][r] = vs[1];
        f32x2 vw = f32x2{work[rt * 2][r], work[rt * 2 + 1][r]} + tcw;
        vw = fma2(bc2(xv[0]), sw0, vw);
        vw = fma2(bc2(xv[1]), sw1, vw);
        vw = fma2(bc2(xv[2]), sw2, vw);
        vw = fma2(bc2(xv[3]), sw3, vw);
        vw = gelu2(vw);
        work[rt * 2][r] = vw[0]; work[rt * 2 + 1][r] = vw[1];
      }
  };
  auto epi_gelu = [&](const float* bias) {
    f32x2 bcv = *(const f32x2*)(bias + colw);
    #pragma unroll
    for (int rt = 0; rt < 2; ++rt)
      #pragma unroll
      for (int r = 0; r < 4; ++r) {
        f32x2 v = f32x2{work[rt * 2][r], work[rt * 2 + 1][r]} + bcv;
        v = gelu2(v);
        work[rt * 2][r] = v[0]; work[rt * 2 + 1][r] = v[1];
      }
  };
  auto epi_gelu_res = [&](const float* bias) {
    f32x2 bcv = *(const f32x2*)(bias + colw);
    #pragma unroll
    for (int rt = 0; rt < 2; ++rt)
      #pragma unroll
      for (int r = 0; r < 4; ++r) {
        f32x2 v = gelu2(f32x2{work[rt * 2][r], work[rt * 2 + 1][r]} + bcv)
                + f32x2{resid[rt * 2][r], resid[rt * 2 + 1][r]};
        resid[rt * 2][r] = v[0]; resid[rt * 2 + 1][r] = v[1];
        work[rt * 2][r] = v[0];  work[rt * 2 + 1][r] = v[1];
      }
  };

  for (int s = 0; s < 10; ++s) {
    const float* tw  = tvecs + s * 512;
    const float* tsk = tvecs + s * 512 + 256;
    // skip -> resid, y1 -> work: ONE lcond pass, two B's, merged epilogue.
    // lact0 overwrite safe: last lact0 readers (blk2-g2 mm) pre-B8 prev step.
    mm_tile2_dual(Acond, wts + 2 * 65536 + wlane, wts + 1 * 65536 + wlane,
                  resid, work);
    epi_bot_dual(tsk, skipbot, tw, w1bot);
    write_act(lact0);
    __syncthreads();                               // B1: y1 in lact0
    // h = gelu(y1 @ W2 + b2) + skip                -> lact1
    mm_tile2(A0, wts + 3 * 65536 + wlane, work);
    epi_gelu_res(b2v);
    write_act(lact1);     // != read buffer: no pre-barrier needed
    __syncthreads();                               // B2: h in lact1
    // 3 residual blocks: g1 lact1->lact0, g2 lact0->lact1
    for (int blk = 0; blk < 3; ++blk) {
      mm_tile2(A1, wts + (4 + blk) * 65536 + wlane, work);
      epi_gelu(blksb1 + blk * 256);
      write_act(lact0);
      __syncthreads();                             // g1 in lact0
      mm_tile2(A0, wts + (7 + blk) * 65536 + wlane, work);
      epi_gelu_res(blksb2 + blk * 256);
      write_act(lact1);
      __syncthreads();                             // g2 in lact1
    }
    // pred = h @ final_w + final_b via MFMA (wave 0); x-update
    if (wave == 0) {
      f32x4 pacc[4];
      mm_tile2(A1, wts + 10 * 65536 + lane * 8, pacc);   // compact fw tile
      if (l16 < 2) {
        f32x4 sc = *(const f32x4*)(stepsc + s * 4);
        #pragma unroll
        for (int ct = 0; ct < 2; ++ct) {
          int col = l16 * 2 + ct;
          float fb = finalb[col];
          #pragma unroll
          for (int rt = 0; rt < 2; ++rt)
            #pragma unroll
            for (int r = 0; r < 4; ++r) {
              int row = rt * 16 + quad * 4 + r;
              float accp = pacc[rt * 2 + ct][r] + fb;
              float xv = lx[row * 4 + col];
              xv = (xv - sc[1] * accp) * sc[0];
              xv = fmaf(sc[2],
                        noises[(size_t)s * nb * 4 + (size_t)(rowbase + row) * 4 + col],
                        xv);
              lx[row * 4 + col] = xv;   // readers only after B9
            }
        }
      }
    }
    __syncthreads();                               // B9: lx + lact1 reads done
  }
  if (tid < 128) {
    float xf = lx[tid];
    xf = fminf(1.0f, fmaxf(-1.0f, xf));
    out[rowbase * 4 + tid] = xf;
  }
}

// ---------------------------------------------------------------------------
extern "C" void kernel_launch(void* const* d_in, const int* in_sizes, int n_in,
                              void* d_out, int out_size, void* d_ws, size_t ws_size,
                              hipStream_t stream) {
  (void)n_in; (void)out_size; (void)ws_size;
  const float* features    = (const float*)d_in[0];
  const float* cond_w      = (const float*)d_in[1];
  const float* cond_b      = (const float*)d_in[2];
  const float* time_w      = (const float*)d_in[3];
  const float* time_b      = (const float*)d_in[4];
  const float* blk0_w1     = (const float*)d_in[5];
  const float* blk0_b1     = (const float*)d_in[6];
  const float* blk0_w2     = (const float*)d_in[7];
  const float* blk0_b2     = (const float*)d_in[8];
  const float* blk0_skip_w = (const float*)d_in[9];
  const float* blk0_skip_b = (const float*)d_in[10];
  const float* blks_w1     = (const float*)d_in[11];
  const float* blks_b1     = (const float*)d_in[12];
  const float* blks_w2     = (const float*)d_in[13];
  const float* blks_b2     = (const float*)d_in[14];
  const float* final_w     = (const float*)d_in[15];
  const float* final_b     = (const float*)d_in[16];

  const int nb = in_sizes[0] / 256;   // batch (32768)

  // workspace layout (bytes, 256-aligned)
  char* ws = (char*)d_ws;
  bf16_t* wts    = (bf16_t*)(ws + 0);        // (10*65536 + 8192) bf16 = 1,327,104 B
  float*  tvecs  = (float*)(ws + 1327104);   // 10 * 512 f32    = 20,480 B
  float*  stepsc = (float*)(ws + 1347584);   // 10 * 4 f32      (pad to 256)
  float*  x0w    = (float*)(ws + 1347840);   // nb*4 f32        = 524,288 B
  float*  noisew = (float*)(ws + 1872128);   // 10*nb*4 f32     = 5,242,880 B
  bf16_t* condw  = (bf16_t*)(ws + 7115008);  // nb*256 bf16     = 16,777,216 B

  wprep_kernel<<<2592, 256, 0, stream>>>(cond_w, blk0_w1, blk0_skip_w, blk0_w2,
                                         blks_w1, blks_w2, final_w, wts);
  prep_kernel<<<10, 256, 0, stream>>>(time_w, time_b, blk0_w1, blk0_b1,
                                      blk0_skip_w, blk0_skip_b, tvecs, stepsc);
  noise_kernel<<<(nb * 44 + 255) / 256, 256, 0, stream>>>(x0w, noisew, nb);
  cond_kernel<<<nb / MTILE, 256, 0, stream>>>(features, wts, cond_b, condw);
  fused_kernel<<<nb / FTILE, 512, 0, stream>>>(
      condw, wts, tvecs, stepsc, x0w, noisew,
      blk0_w1 + 512 * 256, blk0_skip_w + 512 * 256, blk0_b2,
      blks_b1, blks_b2, final_b, (float*)d_out, nb);
}

// Round 13
// 771.161 us; speedup vs baseline: 1.2661x; 1.2661x over previous
//
#include <hip/hip_runtime.h>
#include <stdint.h>
#include <stddef.h>

// ---------------------------------------------------------------------------
// DiffusionActionHead: fully fused 10-step DDPM sampler, bf16 MFMA.
//   B=32768, H=256, A=4, 10 inference steps.
//   1. wprep_kernel  : repack 10 weight matrices + final_w tile -> bf16 frags
//   2. prep_kernel   : per-step temb-derived col-vectors tw1/tskip + scalars
//   3. noise_kernel  : JAX threefry2x32, PARTITIONABLE counter scheme
//   4. cond_kernel   : cond = features @ cond_w + cond_b  (bf16 out)
//   5. fused_kernel  : 10 steps x 9 K=256 GEMMs per 64-row tile.
//      ROUND 13 (post-mortem r12: pred-MFMA's pacc AGPRs broke FTILE=32
//      co-residency (occ 42.8->23.7) and cost 170us -- proving the 2-block
//      overlap WAS real at FTILE=32 (1-blk ~970 -> 2-blk 799) but never beat
//      the MTILE=64 single-block champion r5=779us.
//      This round: champion r5 config EXACTLY + pred-MFMA, where it's free:
//        - MTILE=64, dual GEMM skip+y1, double-buffered lact (9 barriers),
//          packed f32x2 epilogues, KP=272, __launch_bounds__(512,1).
//          LDS 105.5KB -> 1 block/CU (measured occupancy-invariant here,
//          so pacc's AGPR cost cannot hurt).
//        - pred via MFMA on waves 0,1 (wave w: rows w*32..w*32+31): compact
//          fw tile (11th, final_w 256x4 bf16, cols at l16<2). Replaces the
//          4-wave tail of 32 ds_read_b128 + 256 scalar ds_read_b32 +
//          256 fmaf/thread with 2x{16 ds_read_b128 + 32 MFMA}. lfw deleted.
// ---------------------------------------------------------------------------

typedef __bf16 bf16_t;
typedef __bf16 bf16x8 __attribute__((ext_vector_type(8)));
typedef __bf16 bf16x4 __attribute__((ext_vector_type(4)));
typedef __bf16 bf16x2 __attribute__((ext_vector_type(2)));
typedef float  f32x4  __attribute__((ext_vector_type(4)));
typedef float  f32x2  __attribute__((ext_vector_type(2)));

constexpr int KP    = 272;   // LDS row stride in bf16 elems (256 + 16 pad)
constexpr int MTILE = 64;    // rows per workgroup

// ---------------- packed f32x2 helpers -------------------------------------
__device__ __forceinline__ f32x2 bc2(float v) { return f32x2{v, v}; }
__device__ __forceinline__ f32x2 fma2(f32x2 a, f32x2 b, f32x2 c) {
#if __has_builtin(__builtin_elementwise_fma)
  return __builtin_elementwise_fma(a, b, c);
#else
  return f32x2{fmaf(a[0], b[0], c[0]), fmaf(a[1], b[1], c[1])};
#endif
}
__device__ __forceinline__ f32x2 abs2(f32x2 x) {
#if __has_builtin(__builtin_elementwise_abs)
  return __builtin_elementwise_abs(x);
#else
  return f32x2{fabsf(x[0]), fabsf(x[1])};
#endif
}

// ---------------- exact-erf GELU (A&S 7.1.26), scalar and packed ------------
__device__ __forceinline__ float gelu_f(float x) {
  float z  = 0.70710678f * x;
  float az = fabsf(z);
  float t  = __builtin_amdgcn_rcpf(fmaf(0.3275911f, az, 1.0f));
  float e  = __expf(-az * az);
  float p  = fmaf(1.061405429f, t, -1.453152027f);
  p = fmaf(p, t, 1.421413741f);
  p = fmaf(p, t, -0.284496736f);
  p = fmaf(p, t, 0.254829592f);
  float er = fmaf(-(p * t), e, 1.0f);   // erf(|z|)
  er = copysignf(er, z);
  return 0.5f * x * (1.0f + er);
}
// per-half op sequence identical to gelu_f (fma2==fmaf per lane)
__device__ __forceinline__ f32x2 gelu2(f32x2 x) {
  f32x2 z  = bc2(0.70710678f) * x;
  f32x2 az = abs2(z);
  f32x2 d  = fma2(bc2(0.3275911f), az, bc2(1.0f));
  f32x2 t; t[0] = __builtin_amdgcn_rcpf(d[0]); t[1] = __builtin_amdgcn_rcpf(d[1]);
  f32x2 naz = -az * az;
  f32x2 e; e[0] = __expf(naz[0]); e[1] = __expf(naz[1]);
  f32x2 p  = fma2(bc2(1.061405429f), t, bc2(-1.453152027f));
  p = fma2(p, t, bc2(1.421413741f));
  p = fma2(p, t, bc2(-0.284496736f));
  p = fma2(p, t, bc2(0.254829592f));
  f32x2 q  = p * t;
  f32x2 er = fma2(-q, e, bc2(1.0f));
  er[0] = copysignf(er[0], z[0]);
  er[1] = copysignf(er[1], z[1]);
  return (bc2(0.5f) * x) * (bc2(1.0f) + er);
}

// ---------------- JAX threefry2x32 (20 rounds) ------------------------------
#define TFR(a) x0 += x1; x1 = (x1 << (a)) | (x1 >> (32 - (a))); x1 ^= x0;
__device__ __forceinline__ void tf2(uint32_t k0, uint32_t k1,
                                    uint32_t x0, uint32_t x1,
                                    uint32_t& o0, uint32_t& o1) {
  uint32_t k2 = k0 ^ k1 ^ 0x1BD11BDAu;
  x0 += k0; x1 += k1;
  TFR(13) TFR(15) TFR(26) TFR(6)
  x0 += k1; x1 += k2 + 1u;
  TFR(17) TFR(29) TFR(16) TFR(24)
  x0 += k2; x1 += k0 + 2u;
  TFR(13) TFR(15) TFR(26) TFR(6)
  x0 += k0; x1 += k1 + 3u;
  TFR(17) TFR(29) TFR(16) TFR(24)
  x0 += k1; x1 += k2 + 4u;
  TFR(13) TFR(15) TFR(26) TFR(6)
  x0 += k2; x1 += k0 + 5u;
  o0 = x0; o1 = x1;
}
#undef TFR

// uniform bits -> N(0,1) exactly like jax.random.normal (XLA erfinv poly)
__device__ __forceinline__ float nrm_from_bits(uint32_t bits) {
  float f = __uint_as_float((bits >> 9) | 0x3f800000u) - 1.0f;  // [0,1)
  const float lo = -0.99999994f;                                 // nextafter(-1,0)
  float u = fmaxf(lo, __fadd_rn(__fmul_rn(f, 2.0f), lo));        // (hi-lo)==2.0f in f32
  float w = -log1pf(-__fmul_rn(u, u));
  float p;
  if (w < 5.0f) {
    float ww = w - 2.5f;
    p = 2.81022636e-08f;
    p = fmaf(p, ww, 3.43273939e-07f);
    p = fmaf(p, ww, -3.5233877e-06f);
    p = fmaf(p, ww, -4.39150654e-06f);
    p = fmaf(p, ww, 0.00021858087f);
    p = fmaf(p, ww, -0.00125372503f);
    p = fmaf(p, ww, -0.00417768164f);
    p = fmaf(p, ww, 0.246640727f);
    p = fmaf(p, ww, 1.50140941f);
  } else {
    float ww = sqrtf(w) - 3.0f;
    p = -0.000200214257f;
    p = fmaf(p, ww, 0.000100950558f);
    p = fmaf(p, ww, 0.00134934322f);
    p = fmaf(p, ww, -0.00367342844f);
    p = fmaf(p, ww, 0.00573950773f);
    p = fmaf(p, ww, -0.0076224613f);
    p = fmaf(p, ww, 0.00943887047f);
    p = fmaf(p, ww, 1.00167406f);
    p = fmaf(p, ww, 2.83297682f);
  }
  return 1.41421354f * (p * u);   // sqrt(2) * erfinv(u)
}

// ---------------- 64x64 MFMA tile (4 ntiles/wave, cond_kernel) -------------
__device__ __forceinline__ void mm_tile(const bf16_t* __restrict__ A,
                                        const bf16_t* __restrict__ Wp,
                                        f32x4 acc[16]) {
  #pragma unroll
  for (int i = 0; i < 16; ++i) acc[i] = f32x4{0.f, 0.f, 0.f, 0.f};
  #pragma unroll 2
  for (int kc = 0; kc < 8; ++kc) {
    bf16x8 a[4], b[4];
    #pragma unroll
    for (int rt = 0; rt < 4; ++rt)
      a[rt] = *(const bf16x8*)(A + rt * 16 * KP + kc * 32);
    #pragma unroll
    for (int ct = 0; ct < 4; ++ct)
      b[ct] = *(const bf16x8*)(Wp + ct * 4096 + kc * 512);
    #pragma unroll
    for (int rt = 0; rt < 4; ++rt)
      #pragma unroll
      for (int ct = 0; ct < 4; ++ct)
        acc[rt * 4 + ct] =
            __builtin_amdgcn_mfma_f32_16x16x32_bf16(a[rt], b[ct], acc[rt * 4 + ct], 0, 0, 0);
  }
}

// ---------------- 64x32 MFMA tile (2 ntiles/wave, fused_kernel) ------------
__device__ __forceinline__ void mm_tile2(const bf16_t* __restrict__ A,
                                         const bf16_t* __restrict__ Wp,
                                         f32x4 acc[8]) {
  #pragma unroll
  for (int i = 0; i < 8; ++i) acc[i] = f32x4{0.f, 0.f, 0.f, 0.f};
  #pragma unroll 2
  for (int kc = 0; kc < 8; ++kc) {
    bf16x8 a[4], b[2];
    #pragma unroll
    for (int rt = 0; rt < 4; ++rt)
      a[rt] = *(const bf16x8*)(A + rt * 16 * KP + kc * 32);
    #pragma unroll
    for (int ct = 0; ct < 2; ++ct)
      b[ct] = *(const bf16x8*)(Wp + ct * 4096 + kc * 512);
    #pragma unroll
    for (int rt = 0; rt < 4; ++rt)
      #pragma unroll
      for (int ct = 0; ct < 2; ++ct)
        acc[rt * 2 + ct] =
            __builtin_amdgcn_mfma_f32_16x16x32_bf16(a[rt], b[ct], acc[rt * 2 + ct], 0, 0, 0);
  }
}

// 32x32 MFMA tile (2rt x 2ct) for the pred GEMM (rows pre-offset in A)
__device__ __forceinline__ void mm_tile22(const bf16_t* __restrict__ A,
                                          const bf16_t* __restrict__ Wp,
                                          f32x4 acc[4]) {
  #pragma unroll
  for (int i = 0; i < 4; ++i) acc[i] = f32x4{0.f, 0.f, 0.f, 0.f};
  #pragma unroll 2
  for (int kc = 0; kc < 8; ++kc) {
    bf16x8 a[2], b[2];
    #pragma unroll
    for (int rt = 0; rt < 2; ++rt)
      a[rt] = *(const bf16x8*)(A + rt * 16 * KP + kc * 32);
    #pragma unroll
    for (int ct = 0; ct < 2; ++ct)
      b[ct] = *(const bf16x8*)(Wp + ct * 4096 + kc * 512);
    #pragma unroll
    for (int rt = 0; rt < 2; ++rt)
      #pragma unroll
      for (int ct = 0; ct < 2; ++ct)
        acc[rt * 2 + ct] =
            __builtin_amdgcn_mfma_f32_16x16x32_bf16(a[rt], b[ct], acc[rt * 2 + ct], 0, 0, 0);
  }
}

// Dual: one A pass (lcond) feeds TWO B's -> skip (acc1) + y1 (acc2)
__device__ __forceinline__ void mm_tile2_dual(const bf16_t* __restrict__ A,
                                              const bf16_t* __restrict__ W1,
                                              const bf16_t* __restrict__ W2,
                                              f32x4 acc1[8], f32x4 acc2[8]) {
  #pragma unroll
  for (int i = 0; i < 8; ++i) {
    acc1[i] = f32x4{0.f, 0.f, 0.f, 0.f};
    acc2[i] = f32x4{0.f, 0.f, 0.f, 0.f};
  }
  #pragma unroll 2
  for (int kc = 0; kc < 8; ++kc) {
    bf16x8 a[4];
    #pragma unroll
    for (int rt = 0; rt < 4; ++rt)
      a[rt] = *(const bf16x8*)(A + rt * 16 * KP + kc * 32);
    #pragma unroll
    for (int ct = 0; ct < 2; ++ct) {
      bf16x8 b = *(const bf16x8*)(W1 + ct * 4096 + kc * 512);
      #pragma unroll
      for (int rt = 0; rt < 4; ++rt)
        acc1[rt * 2 + ct] =
            __builtin_amdgcn_mfma_f32_16x16x32_bf16(a[rt], b, acc1[rt * 2 + ct], 0, 0, 0);
    }
    #pragma unroll
    for (int ct = 0; ct < 2; ++ct) {
      bf16x8 b = *(const bf16x8*)(W2 + ct * 4096 + kc * 512);
      #pragma unroll
      for (int rt = 0; rt < 4; ++rt)
        acc2[rt * 2 + ct] =
            __builtin_amdgcn_mfma_f32_16x16x32_bf16(a[rt], b, acc2[rt * 2 + ct], 0, 0, 0);
    }
  }
}

// ---------------- kernel 1: weight repack ----------------------------------
// dst element e = [m][nt][kc][lane][j]; value = src_m[k*256 + n],
// COLUMN REMAP: n = (nt>>1)*32 + (lane&15)*2 + (nt&1)
// m==10 (compact): final_w 256x4 zero-padded; col n<4 only for l16<2.
__global__ void wprep_kernel(const float* __restrict__ condw,
                             const float* __restrict__ w1,
                             const float* __restrict__ skw,
                             const float* __restrict__ w2,
                             const float* __restrict__ bw1,
                             const float* __restrict__ bw2,
                             const float* __restrict__ fw,
                             bf16_t* __restrict__ wts) {
  int e = blockIdx.x * 256 + threadIdx.x;
  int m = e >> 16;
  int r = e & 65535;
  int nt = r >> 12, kc = (r >> 9) & 7, lane = (r >> 3) & 63, j = r & 7;
  int n = (nt >> 1) * 32 + (lane & 15) * 2 + (nt & 1);
  int k = kc * 32 + (lane >> 4) * 8 + j;
  if (m == 10) {                               // compact final_w tile
    wts[e] = (n < 4) ? (bf16_t)fw[k * 4 + n] : (bf16_t)0.f;
    return;
  }
  const float* src;
  if      (m == 0) src = condw;
  else if (m == 1) src = w1;                    // blk0_w1 rows 0..255 (cond part)
  else if (m == 2) src = skw;                   // blk0_skip_w rows 0..255
  else if (m == 3) src = w2;                    // blk0_w2
  else if (m <= 6) src = bw1 + (m - 4) * 65536; // blks_w1[i]
  else             src = bw2 + (m - 7) * 65536; // blks_w2[i]
  wts[e] = (bf16_t)src[k * 256 + n];
}

// ---------------- kernel 2: per-step vectors + scalars ---------------------
__global__ void prep_kernel(const float* __restrict__ time_w,
                            const float* __restrict__ time_b,
                            const float* __restrict__ w1,
                            const float* __restrict__ b1,
                            const float* __restrict__ skw,
                            const float* __restrict__ skb,
                            float* __restrict__ tvecs,
                            float* __restrict__ stepsc) {
  int s = blockIdx.x;          // 0..9, t = 90 - 10*s
  int j = threadIdx.x;         // 0..255
  int t = 90 - s * 10;
  float tval = (float)t;
  __shared__ float emb[256];
  __shared__ float temb[256];
  if (j < 128) {
    float freq = expf((float)j * -0.07252236513366287f);  // -ln(1e4)/127
    float e = tval * freq;
    emb[j] = sinf(e);
    emb[j + 128] = cosf(e);
  }
  __syncthreads();
  float a = time_b[j];
  for (int k = 0; k < 256; ++k) a = fmaf(emb[k], time_w[k * 256 + j], a);
  temb[j] = gelu_f(a);
  __syncthreads();
  float v1 = b1[j], v2 = skb[j];
  for (int k = 0; k < 256; ++k) {
    float tk = temb[k];
    v1 = fmaf(tk, w1[(256 + k) * 256 + j], v1);    // blk0_w1 rows 256..511
    v2 = fmaf(tk, skw[(256 + k) * 256 + j], v2);   // blk0_skip_w rows 256..511
  }
  tvecs[s * 512 + j] = v1;         // tw1 (includes b1)
  tvecs[s * 512 + 256 + j] = v2;   // tskip (includes skip_b)
  if (j == 0) {
    float step = (0.02f - 1e-4f) / 99.0f;
    float acp = 1.0f, beta = 0.0f;
    for (int i = 0; i <= t; ++i) {
      beta = fmaf((float)i, step, 1e-4f);
      acp *= (1.0f - beta);
    }
    stepsc[s * 4 + 0] = 1.0f / sqrtf(1.0f - beta);   // 1/sqrt(alpha)
    stepsc[s * 4 + 1] = beta / sqrtf(1.0f - acp);    // b/sqrt(1-acp)
    stepsc[s * 4 + 2] = (t > 0) ? sqrtf(beta) : 0.0f;
    stepsc[s * 4 + 3] = 0.0f;
  }
}

// ---------------- kernel 3: x0 + noises via PARTITIONABLE threefry ---------
__global__ void noise_kernel(float* __restrict__ xout, float* __restrict__ nout, int nb) {
  int gid = blockIdx.x * 256 + threadIdx.x;
  int nx = nb * 4;     // 131072 x0 elements
  int nn = nb * 40;    // 1310720 noise elements
  uint32_t k0, k1, o0, o1;
  if (gid < nx) {
    tf2(0u, 42u, 0u, 999u, k0, k1);                 // fold_in(key(42), 999)
    tf2(k0, k1, 0u, (uint32_t)gid, o0, o1);
    xout[gid] = nrm_from_bits(o0 ^ o1);
  } else if (gid < nx + nn) {
    int i = gid - nx;
    tf2(0u, 42u, 0u, 7u, k0, k1);                   // fold_in(key(42), 7)
    tf2(k0, k1, 0u, (uint32_t)i, o0, o1);
    nout[i] = nrm_from_bits(o0 ^ o1);
  }
}

// ---------------- kernel 4: cond = features @ cond_w + cond_b --------------
__global__ __launch_bounds__(256, 2) void cond_kernel(
    const float* __restrict__ feat, const bf16_t* __restrict__ wts,
    const float* __restrict__ condb, bf16_t* __restrict__ condg) {
  __shared__ __align__(16) bf16_t la[MTILE * KP];
  const int tid = threadIdx.x;
  const int wave = tid >> 6, lane = tid & 63, quad = lane >> 4, l16 = lane & 15;
  const int rowbase = blockIdx.x * MTILE;
  for (int it = 0; it < 16; ++it) {
    int e = (it * 256 + tid) * 4;
    int rr = e >> 8, c = e & 255;
    f32x4 v = *(const f32x4*)(feat + (size_t)(rowbase + rr) * 256 + c);
    bf16x4 bv;
    bv[0] = (bf16_t)v[0]; bv[1] = (bf16_t)v[1];
    bv[2] = (bf16_t)v[2]; bv[3] = (bf16_t)v[3];
    *(bf16x4*)(la + rr * KP + c) = bv;
  }
  __syncthreads();
  f32x4 acc[16];
  mm_tile(la + l16 * KP + quad * 8, wts + wave * 16384 + lane * 8, acc);
  const int c0 = wave * 64 + l16 * 2;            // ct 0,1 -> c0, ct 2,3 -> c0+32
  f32x2 b0 = *(const f32x2*)(condb + c0);
  f32x2 b1 = *(const f32x2*)(condb + c0 + 32);
  #pragma unroll
  for (int rt = 0; rt < 4; ++rt)
    #pragma unroll
    for (int r = 0; r < 4; ++r) {
      int row = rt * 16 + quad * 4 + r;
      bf16x2 p0, p1;
      p0[0] = (bf16_t)(acc[rt * 4 + 0][r] + b0[0]);
      p0[1] = (bf16_t)(acc[rt * 4 + 1][r] + b0[1]);
      p1[0] = (bf16_t)(acc[rt * 4 + 2][r] + b1[0]);
      p1[1] = (bf16_t)(acc[rt * 4 + 3][r] + b1[1]);
      *(bf16x2*)(condg + (size_t)(rowbase + row) * 256 + c0) = p0;
      *(bf16x2*)(condg + (size_t)(rowbase + row) * 256 + c0 + 32) = p1;
    }
}

// ---------------- kernel 5: fused 10-step sampler (512 thr / 8 waves) ------
// r5 champion structure: MTILE=64, dual GEMM, double-buffered lact
// (9 barriers/step), packed epilogues. NEW: pred via MFMA on waves 0,1.
__global__ __launch_bounds__(512, 1) void fused_kernel(
    const bf16_t* __restrict__ condg, const bf16_t* __restrict__ wts,
    const float* __restrict__ tvecs, const float* __restrict__ stepsc,
    const float* __restrict__ x0w, const float* __restrict__ noises,
    const float* __restrict__ w1bot, const float* __restrict__ skipbot,
    const float* __restrict__ b2v, const float* __restrict__ blksb1,
    const float* __restrict__ blksb2,
    const float* __restrict__ finalb, float* __restrict__ out, int nb) {
  __shared__ __align__(16) bf16_t lcond[MTILE * KP];
  __shared__ __align__(16) bf16_t lact0[MTILE * KP];   // double-buffered act
  __shared__ __align__(16) bf16_t lact1[MTILE * KP];
  __shared__ __align__(16) float  lx[MTILE * 4];
  const int tid = threadIdx.x;
  const int wave = tid >> 6, lane = tid & 63, quad = lane >> 4, l16 = lane & 15;
  const int rowbase = blockIdx.x * MTILE;

  // stage cond tile (persists all 10 steps) + x0
  {
    int rr = tid >> 3, c = (tid & 7) * 32;
    const bf16_t* src = condg + (size_t)(rowbase + rr) * 256 + c;
    bf16_t* dst = lcond + rr * KP + c;
    #pragma unroll
    for (int j = 0; j < 4; ++j)
      *(bf16x8*)(dst + j * 8) = *(const bf16x8*)(src + j * 8);
  }
  if (tid < 256) lx[tid] = x0w[rowbase * 4 + tid];
  __syncthreads();

  const bf16_t* Acond = lcond + l16 * KP + quad * 8;
  const bf16_t* A0    = lact0 + l16 * KP + quad * 8;
  const bf16_t* A1    = lact1 + l16 * KP + quad * 8;
  const int colw = wave * 32 + l16 * 2;          // 2 consecutive cols/lane
  const int wlane = wave * 8192 + lane * 8;
  f32x4 resid[8], work[8];

  // pack lane's 2 consecutive cols -> one ds_write_b32 per (rt,r)
  auto write_act = [&](bf16_t* dst) {
    #pragma unroll
    for (int rt = 0; rt < 4; ++rt)
      #pragma unroll
      for (int r = 0; r < 4; ++r) {
        bf16x2 pv;
        pv[0] = (bf16_t)work[rt * 2 + 0][r];
        pv[1] = (bf16_t)work[rt * 2 + 1][r];
        *(bf16x2*)(dst + (rt * 16 + quad * 4 + r) * KP + colw) = pv;
      }
  };
  // merged K=516-factorized epilogue: skip (resid, no gelu) + y1 (work, gelu)
  auto epi_bot_dual = [&](const float* tvsk, const float* botsk,
                          const float* tvw, const float* botw) {
    f32x2 tcs = *(const f32x2*)(tvsk + colw);
    f32x2 ss0 = *(const f32x2*)(botsk + colw);
    f32x2 ss1 = *(const f32x2*)(botsk + 256 + colw);
    f32x2 ss2 = *(const f32x2*)(botsk + 512 + colw);
    f32x2 ss3 = *(const f32x2*)(botsk + 768 + colw);
    f32x2 tcw = *(const f32x2*)(tvw + colw);
    f32x2 sw0 = *(const f32x2*)(botw + colw);
    f32x2 sw1 = *(const f32x2*)(botw + 256 + colw);
    f32x2 sw2 = *(const f32x2*)(botw + 512 + colw);
    f32x2 sw3 = *(const f32x2*)(botw + 768 + colw);
    #pragma unroll
    for (int rt = 0; rt < 4; ++rt)
      #pragma unroll
      for (int r = 0; r < 4; ++r) {
        f32x4 xv = *(const f32x4*)(lx + (rt * 16 + quad * 4 + r) * 4);
        f32x2 vs = f32x2{resid[rt * 2][r], resid[rt * 2 + 1][r]} + tcs;
        vs = fma2(bc2(xv[0]), ss0, vs);
        vs = fma2(bc2(xv[1]), ss1, vs);
        vs = fma2(bc2(xv[2]), ss2, vs);
        vs = fma2(bc2(xv[3]), ss3, vs);
        resid[rt * 2][r] = vs[0]; resid[rt * 2 + 1][r] = vs[1];
        f32x2 vw = f32x2{work[rt * 2][r], work[rt * 2 + 1][r]} + tcw;
        vw = fma2(bc2(xv[0]), sw0, vw);
        vw = fma2(bc2(xv[1]), sw1, vw);
        vw = fma2(bc2(xv[2]), sw2, vw);
        vw = fma2(bc2(xv[3]), sw3, vw);
        vw = gelu2(vw);
        work[rt * 2][r] = vw[0]; work[rt * 2 + 1][r] = vw[1];
      }
  };
  auto epi_gelu = [&](const float* bias) {
    f32x2 bcv = *(const f32x2*)(bias + colw);
    #pragma unroll
    for (int rt = 0; rt < 4; ++rt)
      #pragma unroll
      for (int r = 0; r < 4; ++r) {
        f32x2 v = f32x2{work[rt * 2][r], work[rt * 2 + 1][r]} + bcv;
        v = gelu2(v);
        work[rt * 2][r] = v[0]; work[rt * 2 + 1][r] = v[1];
      }
  };
  auto epi_gelu_res = [&](const float* bias) {
    f32x2 bcv = *(const f32x2*)(bias + colw);
    #pragma unroll
    for (int rt = 0; rt < 4; ++rt)
      #pragma unroll
      for (int r = 0; r < 4; ++r) {
        f32x2 v = gelu2(f32x2{work[rt * 2][r], work[rt * 2 + 1][r]} + bcv)
                + f32x2{resid[rt * 2][r], resid[rt * 2 + 1][r]};
        resid[rt * 2][r] = v[0]; resid[rt * 2 + 1][r] = v[1];
        work[rt * 2][r] = v[0];  work[rt * 2 + 1][r] = v[1];
      }
  };

  for (int s = 0; s < 10; ++s) {
    const float* tw  = tvecs + s * 512;
    const float* tsk = tvecs + s * 512 + 256;
    // skip -> resid, y1 -> work: ONE lcond pass, two B's, merged epilogue.
    // lact0 overwrite safe: last lact0 readers (blk2-g2 mm) pre-B8 prev step.
    mm_tile2_dual(Acond, wts + 2 * 65536 + wlane, wts + 1 * 65536 + wlane,
                  resid, work);
    epi_bot_dual(tsk, skipbot, tw, w1bot);
    write_act(lact0);
    __syncthreads();                               // B1: y1 in lact0
    // h = gelu(y1 @ W2 + b2) + skip                -> lact1
    mm_tile2(A0, wts + 3 * 65536 + wlane, work);
    epi_gelu_res(b2v);
    write_act(lact1);     // != read buffer: no pre-barrier needed
    __syncthreads();                               // B2: h in lact1
    // 3 residual blocks: g1 lact1->lact0, g2 lact0->lact1
    for (int blk = 0; blk < 3; ++blk) {
      mm_tile2(A1, wts + (4 + blk) * 65536 + wlane, work);
      epi_gelu(blksb1 + blk * 256);
      write_act(lact0);
      __syncthreads();                             // g1 in lact0
      mm_tile2(A0, wts + (7 + blk) * 65536 + wlane, work);
      epi_gelu_res(blksb2 + blk * 256);
      write_act(lact1);
      __syncthreads();                             // g2 in lact1
    }
    // pred = h @ final_w + final_b via MFMA (waves 0,1: 32 rows each)
    if (wave < 2) {
      f32x4 pacc[4];
      mm_tile22(lact1 + (wave * 32 + l16) * KP + quad * 8,
                wts + 10 * 65536 + lane * 8, pacc);   // compact fw tile
      if (l16 < 2) {
        f32x4 sc = *(const f32x4*)(stepsc + s * 4);
        #pragma unroll
        for (int ct = 0; ct < 2; ++ct) {
          int col = l16 * 2 + ct;
          float fb = finalb[col];
          #pragma unroll
          for (int rt = 0; rt < 2; ++rt)
            #pragma unroll
            for (int r = 0; r < 4; ++r) {
              int row = wave * 32 + rt * 16 + quad * 4 + r;
              float accp = pacc[rt * 2 + ct][r] + fb;
              float xv = lx[row * 4 + col];
              xv = (xv - sc[1] * accp) * sc[0];
              xv = fmaf(sc[2],
                        noises[(size_t)s * nb * 4 + (size_t)(rowbase + row) * 4 + col],
                        xv);
              lx[row * 4 + col] = xv;   // readers only after B9
            }
        }
      }
    }
    __syncthreads();                               // B9: lx + lact1 reads done
  }
  if (tid < 256) {
    float xf = lx[tid];
    xf = fminf(1.0f, fmaxf(-1.0f, xf));
    out[rowbase * 4 + tid] = xf;
  }
}

// ---------------------------------------------------------------------------
extern "C" void kernel_launch(void* const* d_in, const int* in_sizes, int n_in,
                              void* d_out, int out_size, void* d_ws, size_t ws_size,
                              hipStream_t stream) {
  (void)n_in; (void)out_size; (void)ws_size;
  const float* features    = (const float*)d_in[0];
  const float* cond_w      = (const float*)d_in[1];
  const float* cond_b      = (const float*)d_in[2];
  const float* time_w      = (const float*)d_in[3];
  const float* time_b      = (const float*)d_in[4];
  const float* blk0_w1     = (const float*)d_in[5];
  const float* blk0_b1     = (const float*)d_in[6];
  const float* blk0_w2     = (const float*)d_in[7];
  const float* blk0_b2     = (const float*)d_in[8];
  const float* blk0_skip_w = (const float*)d_in[9];
  const float* blk0_skip_b = (const float*)d_in[10];
  const float* blks_w1     = (const float*)d_in[11];
  const float* blks_b1     = (const float*)d_in[12];
  const float* blks_w2     = (const float*)d_in[13];
  const float* blks_b2     = (const float*)d_in[14];
  const float* final_w     = (const float*)d_in[15];
  const float* final_b     = (const float*)d_in[16];

  const int nb = in_sizes[0] / 256;   // batch (32768)

  // workspace layout (bytes, 256-aligned)
  char* ws = (char*)d_ws;
  bf16_t* wts    = (bf16_t*)(ws + 0);        // (10*65536 + 8192) bf16 = 1,327,104 B
  float*  tvecs  = (float*)(ws + 1327104);   // 10 * 512 f32    = 20,480 B
  float*  stepsc = (float*)(ws + 1347584);   // 10 * 4 f32      (pad to 256)
  float*  x0w    = (float*)(ws + 1347840);   // nb*4 f32        = 524,288 B
  float*  noisew = (float*)(ws + 1872128);   // 10*nb*4 f32     = 5,242,880 B
  bf16_t* condw  = (bf16_t*)(ws + 7115008);  // nb*256 bf16     = 16,777,216 B

  wprep_kernel<<<2592, 256, 0, stream>>>(cond_w, blk0_w1, blk0_skip_w, blk0_w2,
                                         blks_w1, blks_w2, final_w, wts);
  prep_kernel<<<10, 256, 0, stream>>>(time_w, time_b, blk0_w1, blk0_b1,
                                      blk0_skip_w, blk0_skip_b, tvecs, stepsc);
  noise_kernel<<<(nb * 44 + 255) / 256, 256, 0, stream>>>(x0w, noisew, nb);
  cond_kernel<<<nb / MTILE, 256, 0, stream>>>(features, wts, cond_b, condw);
  fused_kernel<<<nb / MTILE, 512, 0, stream>>>(
      condw, wts, tvecs, stepsc, x0w, noisew,
      blk0_w1 + 512 * 256, blk0_skip_w + 512 * 256, blk0_b2,
      blks_b1, blks_b2, final_b, (float*)d_out, nb);
}

// Round 14
// 746.242 us; speedup vs baseline: 1.3083x; 1.0334x over previous
//
#include <hip/hip_runtime.h>
#include <stdint.h>
#include <stddef.h>

// ---------------------------------------------------------------------------
// DiffusionActionHead: fully fused 10-step DDPM sampler, bf16 MFMA.
//   B=32768, H=256, A=4, 10 inference steps.
//   1. wprep_kernel  : repack 10 weight matrices + final_w tile -> bf16 frags
//   2. prep_kernel   : per-step temb-derived col-vectors tw1/tskip + scalars
//   3. noise_kernel  : JAX threefry2x32, PARTITIONABLE counter scheme
//   4. cond_kernel   : cond = features @ cond_w + cond_b  (bf16 out)
//   5. fused_kernel  : 10 steps x 9 K=256 GEMMs per 64-row tile.
//      ROUND 14 (r13 = champion 749us fused; VALUBusy 53% is the bound,
//      occupancy-invariant => cut VALU instruction count arithmetically):
//        - bias/tvec FOLDED INTO MFMA ACC INIT: acc[rt*2+ct] lanes are 4 rows
//          of ONE column -> per-column constants (tskip/tw1/b2/blksb*/final_b)
//          init C; matrix pipe does the add. ~140 pk-adds/step/thread removed.
//        - gelu2 erf: A&S 7.1.26 (4-term) -> 7.1.25 (3-term, |err|<=2.5e-5
//          << bf16 rounding 4e-3): saves 2 fma2 x 128 gelu2/step/thread.
//        - step-invariant column constants (skipbot/w1bot/biases) hoisted to
//          registers pre-loop (~130 arch VGPR, harmless at 1 block).
//        - structure unchanged from r13: MTILE=64, dual GEMM, dbuf lact
//          (9 barriers), pred-MFMA on waves 0,1, KP=272, (512,1) bounds.
// ---------------------------------------------------------------------------

typedef __bf16 bf16_t;
typedef __bf16 bf16x8 __attribute__((ext_vector_type(8)));
typedef __bf16 bf16x4 __attribute__((ext_vector_type(4)));
typedef __bf16 bf16x2 __attribute__((ext_vector_type(2)));
typedef float  f32x4  __attribute__((ext_vector_type(4)));
typedef float  f32x2  __attribute__((ext_vector_type(2)));

constexpr int KP    = 272;   // LDS row stride in bf16 elems (256 + 16 pad)
constexpr int MTILE = 64;    // rows per workgroup

// ---------------- packed f32x2 helpers -------------------------------------
__device__ __forceinline__ f32x2 bc2(float v) { return f32x2{v, v}; }
__device__ __forceinline__ f32x2 fma2(f32x2 a, f32x2 b, f32x2 c) {
#if __has_builtin(__builtin_elementwise_fma)
  return __builtin_elementwise_fma(a, b, c);
#else
  return f32x2{fmaf(a[0], b[0], c[0]), fmaf(a[1], b[1], c[1])};
#endif
}
__device__ __forceinline__ f32x2 abs2(f32x2 x) {
#if __has_builtin(__builtin_elementwise_abs)
  return __builtin_elementwise_abs(x);
#else
  return f32x2{fabsf(x[0]), fabsf(x[1])};
#endif
}

// ---------------- exact-erf GELU (A&S 7.1.26) for prep_kernel ---------------
__device__ __forceinline__ float gelu_f(float x) {
  float z  = 0.70710678f * x;
  float az = fabsf(z);
  float t  = __builtin_amdgcn_rcpf(fmaf(0.3275911f, az, 1.0f));
  float e  = __expf(-az * az);
  float p  = fmaf(1.061405429f, t, -1.453152027f);
  p = fmaf(p, t, 1.421413741f);
  p = fmaf(p, t, -0.284496736f);
  p = fmaf(p, t, 0.254829592f);
  float er = fmaf(-(p * t), e, 1.0f);   // erf(|z|)
  er = copysignf(er, z);
  return 0.5f * x * (1.0f + er);
}
// packed GELU via A&S 7.1.25 (3-term, |erf err|<=2.5e-5 -> |gelu err|~1e-4,
// far below the bf16 activation rounding ~4e-3 already in the pipeline)
__device__ __forceinline__ f32x2 gelu2(f32x2 x) {
  f32x2 z  = bc2(0.70710678f) * x;
  f32x2 az = abs2(z);
  f32x2 d  = fma2(bc2(0.47047f), az, bc2(1.0f));
  f32x2 t; t[0] = __builtin_amdgcn_rcpf(d[0]); t[1] = __builtin_amdgcn_rcpf(d[1]);
  f32x2 naz = -az * az;
  f32x2 e; e[0] = __expf(naz[0]); e[1] = __expf(naz[1]);
  f32x2 q  = fma2(bc2(0.7478556f), t, bc2(-0.0958798f));
  q = fma2(q, t, bc2(0.3480242f));
  f32x2 er = fma2(-(q * t), e, bc2(1.0f));
  er[0] = copysignf(er[0], z[0]);
  er[1] = copysignf(er[1], z[1]);
  return (bc2(0.5f) * x) * (bc2(1.0f) + er);
}

// ---------------- JAX threefry2x32 (20 rounds) ------------------------------
#define TFR(a) x0 += x1; x1 = (x1 << (a)) | (x1 >> (32 - (a))); x1 ^= x0;
__device__ __forceinline__ void tf2(uint32_t k0, uint32_t k1,
                                    uint32_t x0, uint32_t x1,
                                    uint32_t& o0, uint32_t& o1) {
  uint32_t k2 = k0 ^ k1 ^ 0x1BD11BDAu;
  x0 += k0; x1 += k1;
  TFR(13) TFR(15) TFR(26) TFR(6)
  x0 += k1; x1 += k2 + 1u;
  TFR(17) TFR(29) TFR(16) TFR(24)
  x0 += k2; x1 += k0 + 2u;
  TFR(13) TFR(15) TFR(26) TFR(6)
  x0 += k0; x1 += k1 + 3u;
  TFR(17) TFR(29) TFR(16) TFR(24)
  x0 += k1; x1 += k2 + 4u;
  TFR(13) TFR(15) TFR(26) TFR(6)
  x0 += k2; x1 += k0 + 5u;
  o0 = x0; o1 = x1;
}
#undef TFR

// uniform bits -> N(0,1) exactly like jax.random.normal (XLA erfinv poly)
__device__ __forceinline__ float nrm_from_bits(uint32_t bits) {
  float f = __uint_as_float((bits >> 9) | 0x3f800000u) - 1.0f;  // [0,1)
  const float lo = -0.99999994f;                                 // nextafter(-1,0)
  float u = fmaxf(lo, __fadd_rn(__fmul_rn(f, 2.0f), lo));        // (hi-lo)==2.0f in f32
  float w = -log1pf(-__fmul_rn(u, u));
  float p;
  if (w < 5.0f) {
    float ww = w - 2.5f;
    p = 2.81022636e-08f;
    p = fmaf(p, ww, 3.43273939e-07f);
    p = fmaf(p, ww, -3.5233877e-06f);
    p = fmaf(p, ww, -4.39150654e-06f);
    p = fmaf(p, ww, 0.00021858087f);
    p = fmaf(p, ww, -0.00125372503f);
    p = fmaf(p, ww, -0.00417768164f);
    p = fmaf(p, ww, 0.246640727f);
    p = fmaf(p, ww, 1.50140941f);
  } else {
    float ww = sqrtf(w) - 3.0f;
    p = -0.000200214257f;
    p = fmaf(p, ww, 0.000100950558f);
    p = fmaf(p, ww, 0.00134934322f);
    p = fmaf(p, ww, -0.00367342844f);
    p = fmaf(p, ww, 0.00573950773f);
    p = fmaf(p, ww, -0.0076224613f);
    p = fmaf(p, ww, 0.00943887047f);
    p = fmaf(p, ww, 1.00167406f);
    p = fmaf(p, ww, 2.83297682f);
  }
  return 1.41421354f * (p * u);   // sqrt(2) * erfinv(u)
}

// ---------------- 64x64 MFMA tile (4 ntiles/wave, cond_kernel) -------------
__device__ __forceinline__ void mm_tile(const bf16_t* __restrict__ A,
                                        const bf16_t* __restrict__ Wp,
                                        f32x4 acc[16]) {
  #pragma unroll
  for (int i = 0; i < 16; ++i) acc[i] = f32x4{0.f, 0.f, 0.f, 0.f};
  #pragma unroll 2
  for (int kc = 0; kc < 8; ++kc) {
    bf16x8 a[4], b[4];
    #pragma unroll
    for (int rt = 0; rt < 4; ++rt)
      a[rt] = *(const bf16x8*)(A + rt * 16 * KP + kc * 32);
    #pragma unroll
    for (int ct = 0; ct < 4; ++ct)
      b[ct] = *(const bf16x8*)(Wp + ct * 4096 + kc * 512);
    #pragma unroll
    for (int rt = 0; rt < 4; ++rt)
      #pragma unroll
      for (int ct = 0; ct < 4; ++ct)
        acc[rt * 4 + ct] =
            __builtin_amdgcn_mfma_f32_16x16x32_bf16(a[rt], b[ct], acc[rt * 4 + ct], 0, 0, 0);
  }
}

// ---------------- 64x32 MFMA tile, bias-folded C init ----------------------
// acc[rt*2+ct] lanes = 4 rows of column (colw+ct) -> init with ini[ct].
__device__ __forceinline__ void mm_tile2(const bf16_t* __restrict__ A,
                                         const bf16_t* __restrict__ Wp,
                                         f32x4 acc[8], f32x2 ini) {
  #pragma unroll
  for (int rt = 0; rt < 4; ++rt)
    #pragma unroll
    for (int ct = 0; ct < 2; ++ct)
      acc[rt * 2 + ct] = f32x4{ini[ct], ini[ct], ini[ct], ini[ct]};
  #pragma unroll 2
  for (int kc = 0; kc < 8; ++kc) {
    bf16x8 a[4], b[2];
    #pragma unroll
    for (int rt = 0; rt < 4; ++rt)
      a[rt] = *(const bf16x8*)(A + rt * 16 * KP + kc * 32);
    #pragma unroll
    for (int ct = 0; ct < 2; ++ct)
      b[ct] = *(const bf16x8*)(Wp + ct * 4096 + kc * 512);
    #pragma unroll
    for (int rt = 0; rt < 4; ++rt)
      #pragma unroll
      for (int ct = 0; ct < 2; ++ct)
        acc[rt * 2 + ct] =
            __builtin_amdgcn_mfma_f32_16x16x32_bf16(a[rt], b[ct], acc[rt * 2 + ct], 0, 0, 0);
  }
}

// 32x32 MFMA tile for the pred GEMM (rows pre-offset in A), bias-folded
__device__ __forceinline__ void mm_tile22(const bf16_t* __restrict__ A,
                                          const bf16_t* __restrict__ Wp,
                                          f32x4 acc[4], f32x2 ini) {
  #pragma unroll
  for (int rt = 0; rt < 2; ++rt)
    #pragma unroll
    for (int ct = 0; ct < 2; ++ct)
      acc[rt * 2 + ct] = f32x4{ini[ct], ini[ct], ini[ct], ini[ct]};
  #pragma unroll 2
  for (int kc = 0; kc < 8; ++kc) {
    bf16x8 a[2], b[2];
    #pragma unroll
    for (int rt = 0; rt < 2; ++rt)
      a[rt] = *(const bf16x8*)(A + rt * 16 * KP + kc * 32);
    #pragma unroll
    for (int ct = 0; ct < 2; ++ct)
      b[ct] = *(const bf16x8*)(Wp + ct * 4096 + kc * 512);
    #pragma unroll
    for (int rt = 0; rt < 2; ++rt)
      #pragma unroll
      for (int ct = 0; ct < 2; ++ct)
        acc[rt * 2 + ct] =
            __builtin_amdgcn_mfma_f32_16x16x32_bf16(a[rt], b[ct], acc[rt * 2 + ct], 0, 0, 0);
  }
}

// Dual: one A pass (lcond) feeds TWO B's -> skip (acc1) + y1 (acc2),
// each with its own per-column C init (tskip / tw1).
__device__ __forceinline__ void mm_tile2_dual(const bf16_t* __restrict__ A,
                                              const bf16_t* __restrict__ W1,
                                              const bf16_t* __restrict__ W2,
                                              f32x4 acc1[8], f32x4 acc2[8],
                                              f32x2 ini1, f32x2 ini2) {
  #pragma unroll
  for (int rt = 0; rt < 4; ++rt)
    #pragma unroll
    for (int ct = 0; ct < 2; ++ct) {
      acc1[rt * 2 + ct] = f32x4{ini1[ct], ini1[ct], ini1[ct], ini1[ct]};
      acc2[rt * 2 + ct] = f32x4{ini2[ct], ini2[ct], ini2[ct], ini2[ct]};
    }
  #pragma unroll 2
  for (int kc = 0; kc < 8; ++kc) {
    bf16x8 a[4];
    #pragma unroll
    for (int rt = 0; rt < 4; ++rt)
      a[rt] = *(const bf16x8*)(A + rt * 16 * KP + kc * 32);
    #pragma unroll
    for (int ct = 0; ct < 2; ++ct) {
      bf16x8 b = *(const bf16x8*)(W1 + ct * 4096 + kc * 512);
      #pragma unroll
      for (int rt = 0; rt < 4; ++rt)
        acc1[rt * 2 + ct] =
            __builtin_amdgcn_mfma_f32_16x16x32_bf16(a[rt], b, acc1[rt * 2 + ct], 0, 0, 0);
    }
    #pragma unroll
    for (int ct = 0; ct < 2; ++ct) {
      bf16x8 b = *(const bf16x8*)(W2 + ct * 4096 + kc * 512);
      #pragma unroll
      for (int rt = 0; rt < 4; ++rt)
        acc2[rt * 2 + ct] =
            __builtin_amdgcn_mfma_f32_16x16x32_bf16(a[rt], b, acc2[rt * 2 + ct], 0, 0, 0);
    }
  }
}

// ---------------- kernel 1: weight repack ----------------------------------
// dst element e = [m][nt][kc][lane][j]; value = src_m[k*256 + n],
// COLUMN REMAP: n = (nt>>1)*32 + (lane&15)*2 + (nt&1)
// m==10 (compact): final_w 256x4 zero-padded; col n<4 only for l16<2.
__global__ void wprep_kernel(const float* __restrict__ condw,
                             const float* __restrict__ w1,
                             const float* __restrict__ skw,
                             const float* __restrict__ w2,
                             const float* __restrict__ bw1,
                             const float* __restrict__ bw2,
                             const float* __restrict__ fw,
                             bf16_t* __restrict__ wts) {
  int e = blockIdx.x * 256 + threadIdx.x;
  int m = e >> 16;
  int r = e & 65535;
  int nt = r >> 12, kc = (r >> 9) & 7, lane = (r >> 3) & 63, j = r & 7;
  int n = (nt >> 1) * 32 + (lane & 15) * 2 + (nt & 1);
  int k = kc * 32 + (lane >> 4) * 8 + j;
  if (m == 10) {                               // compact final_w tile
    wts[e] = (n < 4) ? (bf16_t)fw[k * 4 + n] : (bf16_t)0.f;
    return;
  }
  const float* src;
  if      (m == 0) src = condw;
  else if (m == 1) src = w1;                    // blk0_w1 rows 0..255 (cond part)
  else if (m == 2) src = skw;                   // blk0_skip_w rows 0..255
  else if (m == 3) src = w2;                    // blk0_w2
  else if (m <= 6) src = bw1 + (m - 4) * 65536; // blks_w1[i]
  else             src = bw2 + (m - 7) * 65536; // blks_w2[i]
  wts[e] = (bf16_t)src[k * 256 + n];
}

// ---------------- kernel 2: per-step vectors + scalars ---------------------
__global__ void prep_kernel(const float* __restrict__ time_w,
                            const float* __restrict__ time_b,
                            const float* __restrict__ w1,
                            const float* __restrict__ b1,
                            const float* __restrict__ skw,
                            const float* __restrict__ skb,
                            float* __restrict__ tvecs,
                            float* __restrict__ stepsc) {
  int s = blockIdx.x;          // 0..9, t = 90 - 10*s
  int j = threadIdx.x;         // 0..255
  int t = 90 - s * 10;
  float tval = (float)t;
  __shared__ float emb[256];
  __shared__ float temb[256];
  if (j < 128) {
    float freq = expf((float)j * -0.07252236513366287f);  // -ln(1e4)/127
    float e = tval * freq;
    emb[j] = sinf(e);
    emb[j + 128] = cosf(e);
  }
  __syncthreads();
  float a = time_b[j];
  for (int k = 0; k < 256; ++k) a = fmaf(emb[k], time_w[k * 256 + j], a);
  temb[j] = gelu_f(a);
  __syncthreads();
  float v1 = b1[j], v2 = skb[j];
  for (int k = 0; k < 256; ++k) {
    float tk = temb[k];
    v1 = fmaf(tk, w1[(256 + k) * 256 + j], v1);    // blk0_w1 rows 256..511
    v2 = fmaf(tk, skw[(256 + k) * 256 + j], v2);   // blk0_skip_w rows 256..511
  }
  tvecs[s * 512 + j] = v1;         // tw1 (includes b1)
  tvecs[s * 512 + 256 + j] = v2;   // tskip (includes skip_b)
  if (j == 0) {
    float step = (0.02f - 1e-4f) / 99.0f;
    float acp = 1.0f, beta = 0.0f;
    for (int i = 0; i <= t; ++i) {
      beta = fmaf((float)i, step, 1e-4f);
      acp *= (1.0f - beta);
    }
    stepsc[s * 4 + 0] = 1.0f / sqrtf(1.0f - beta);   // 1/sqrt(alpha)
    stepsc[s * 4 + 1] = beta / sqrtf(1.0f - acp);    // b/sqrt(1-acp)
    stepsc[s * 4 + 2] = (t > 0) ? sqrtf(beta) : 0.0f;
    stepsc[s * 4 + 3] = 0.0f;
  }
}

// ---------------- kernel 3: x0 + noises via PARTITIONABLE threefry ---------
__global__ void noise_kernel(float* __restrict__ xout, float* __restrict__ nout, int nb) {
  int gid = blockIdx.x * 256 + threadIdx.x;
  int nx = nb * 4;     // 131072 x0 elements
  int nn = nb * 40;    // 1310720 noise elements
  uint32_t k0, k1, o0, o1;
  if (gid < nx) {
    tf2(0u, 42u, 0u, 999u, k0, k1);                 // fold_in(key(42), 999)
    tf2(k0, k1, 0u, (uint32_t)gid, o0, o1);
    xout[gid] = nrm_from_bits(o0 ^ o1);
  } else if (gid < nx + nn) {
    int i = gid - nx;
    tf2(0u, 42u, 0u, 7u, k0, k1);                   // fold_in(key(42), 7)
    tf2(k0, k1, 0u, (uint32_t)i, o0, o1);
    nout[i] = nrm_from_bits(o0 ^ o1);
  }
}

// ---------------- kernel 4: cond = features @ cond_w + cond_b --------------
__global__ __launch_bounds__(256, 2) void cond_kernel(
    const float* __restrict__ feat, const bf16_t* __restrict__ wts,
    const float* __restrict__ condb, bf16_t* __restrict__ condg) {
  __shared__ __align__(16) bf16_t la[MTILE * KP];
  const int tid = threadIdx.x;
  const int wave = tid >> 6, lane = tid & 63, quad = lane >> 4, l16 = lane & 15;
  const int rowbase = blockIdx.x * MTILE;
  for (int it = 0; it < 16; ++it) {
    int e = (it * 256 + tid) * 4;
    int rr = e >> 8, c = e & 255;
    f32x4 v = *(const f32x4*)(feat + (size_t)(rowbase + rr) * 256 + c);
    bf16x4 bv;
    bv[0] = (bf16_t)v[0]; bv[1] = (bf16_t)v[1];
    bv[2] = (bf16_t)v[2]; bv[3] = (bf16_t)v[3];
    *(bf16x4*)(la + rr * KP + c) = bv;
  }
  __syncthreads();
  f32x4 acc[16];
  mm_tile(la + l16 * KP + quad * 8, wts + wave * 16384 + lane * 8, acc);
  const int c0 = wave * 64 + l16 * 2;            // ct 0,1 -> c0, ct 2,3 -> c0+32
  f32x2 b0 = *(const f32x2*)(condb + c0);
  f32x2 b1 = *(const f32x2*)(condb + c0 + 32);
  #pragma unroll
  for (int rt = 0; rt < 4; ++rt)
    #pragma unroll
    for (int r = 0; r < 4; ++r) {
      int row = rt * 16 + quad * 4 + r;
      bf16x2 p0, p1;
      p0[0] = (bf16_t)(acc[rt * 4 + 0][r] + b0[0]);
      p0[1] = (bf16_t)(acc[rt * 4 + 1][r] + b0[1]);
      p1[0] = (bf16_t)(acc[rt * 4 + 2][r] + b1[0]);
      p1[1] = (bf16_t)(acc[rt * 4 + 3][r] + b1[1]);
      *(bf16x2*)(condg + (size_t)(rowbase + row) * 256 + c0) = p0;
      *(bf16x2*)(condg + (size_t)(rowbase + row) * 256 + c0 + 32) = p1;
    }
}

// ---------------- kernel 5: fused 10-step sampler (512 thr / 8 waves) ------
// r13 champion structure + bias-folded MFMA C init + 3-term gelu.
__global__ __launch_bounds__(512, 1) void fused_kernel(
    const bf16_t* __restrict__ condg, const bf16_t* __restrict__ wts,
    const float* __restrict__ tvecs, const float* __restrict__ stepsc,
    const float* __restrict__ x0w, const float* __restrict__ noises,
    const float* __restrict__ w1bot, const float* __restrict__ skipbot,
    const float* __restrict__ b2v, const float* __restrict__ blksb1,
    const float* __restrict__ blksb2,
    const float* __restrict__ finalb, float* __restrict__ out, int nb) {
  __shared__ __align__(16) bf16_t lcond[MTILE * KP];
  __shared__ __align__(16) bf16_t lact0[MTILE * KP];   // double-buffered act
  __shared__ __align__(16) bf16_t lact1[MTILE * KP];
  __shared__ __align__(16) float  lx[MTILE * 4];
  const int tid = threadIdx.x;
  const int wave = tid >> 6, lane = tid & 63, quad = lane >> 4, l16 = lane & 15;
  const int rowbase = blockIdx.x * MTILE;

  // stage cond tile (persists all 10 steps) + x0
  {
    int rr = tid >> 3, c = (tid & 7) * 32;
    const bf16_t* src = condg + (size_t)(rowbase + rr) * 256 + c;
    bf16_t* dst = lcond + rr * KP + c;
    #pragma unroll
    for (int j = 0; j < 4; ++j)
      *(bf16x8*)(dst + j * 8) = *(const bf16x8*)(src + j * 8);
  }
  if (tid < 256) lx[tid] = x0w[rowbase * 4 + tid];
  __syncthreads();

  const bf16_t* Acond = lcond + l16 * KP + quad * 8;
  const bf16_t* A0    = lact0 + l16 * KP + quad * 8;
  const bf16_t* A1    = lact1 + l16 * KP + quad * 8;
  const int colw = wave * 32 + l16 * 2;          // 2 consecutive cols/lane
  const int wlane = wave * 8192 + lane * 8;
  f32x4 resid[8], work[8];

  // step-invariant per-column constants, hoisted to registers
  const f32x2 ss0 = *(const f32x2*)(skipbot + colw);
  const f32x2 ss1 = *(const f32x2*)(skipbot + 256 + colw);
  const f32x2 ss2 = *(const f32x2*)(skipbot + 512 + colw);
  const f32x2 ss3 = *(const f32x2*)(skipbot + 768 + colw);
  const f32x2 sw0 = *(const f32x2*)(w1bot + colw);
  const f32x2 sw1 = *(const f32x2*)(w1bot + 256 + colw);
  const f32x2 sw2 = *(const f32x2*)(w1bot + 512 + colw);
  const f32x2 sw3 = *(const f32x2*)(w1bot + 768 + colw);
  const f32x2 b2c = *(const f32x2*)(b2v + colw);
  f32x2 g1c[3], g2c[3];
  #pragma unroll
  for (int blk = 0; blk < 3; ++blk) {
    g1c[blk] = *(const f32x2*)(blksb1 + blk * 256 + colw);
    g2c[blk] = *(const f32x2*)(blksb2 + blk * 256 + colw);
  }
  f32x2 fbc;
  {
    int bi = (l16 < 2) ? (int)(l16 * 2) : 0;   // valid lanes only; rest unused
    fbc[0] = finalb[bi]; fbc[1] = finalb[bi + 1];
  }

  // pack lane's 2 consecutive cols -> one ds_write_b32 per (rt,r)
  auto write_act = [&](bf16_t* dst) {
    #pragma unroll
    for (int rt = 0; rt < 4; ++rt)
      #pragma unroll
      for (int r = 0; r < 4; ++r) {
        bf16x2 pv;
        pv[0] = (bf16_t)work[rt * 2 + 0][r];
        pv[1] = (bf16_t)work[rt * 2 + 1][r];
        *(bf16x2*)(dst + (rt * 16 + quad * 4 + r) * KP + colw) = pv;
      }
  };
  // merged K=516-factorized epilogue: x@bot add (tvec already in acc init);
  // skip stays linear in resid, y1 gets gelu into work.
  auto epi_bot_dual = [&]() {
    #pragma unroll
    for (int rt = 0; rt < 4; ++rt)
      #pragma unroll
      for (int r = 0; r < 4; ++r) {
        f32x4 xv = *(const f32x4*)(lx + (rt * 16 + quad * 4 + r) * 4);
        f32x2 vs = f32x2{resid[rt * 2][r], resid[rt * 2 + 1][r]};
        vs = fma2(bc2(xv[0]), ss0, vs);
        vs = fma2(bc2(xv[1]), ss1, vs);
        vs = fma2(bc2(xv[2]), ss2, vs);
        vs = fma2(bc2(xv[3]), ss3, vs);
        resid[rt * 2][r] = vs[0]; resid[rt * 2 + 1][r] = vs[1];
        f32x2 vw = f32x2{work[rt * 2][r], work[rt * 2 + 1][r]};
        vw = fma2(bc2(xv[0]), sw0, vw);
        vw = fma2(bc2(xv[1]), sw1, vw);
        vw = fma2(bc2(xv[2]), sw2, vw);
        vw = fma2(bc2(xv[3]), sw3, vw);
        vw = gelu2(vw);
        work[rt * 2][r] = vw[0]; work[rt * 2 + 1][r] = vw[1];
      }
  };
  auto epi_gelu = [&]() {        // bias already in acc init
    #pragma unroll
    for (int rt = 0; rt < 4; ++rt)
      #pragma unroll
      for (int r = 0; r < 4; ++r) {
        f32x2 v = gelu2(f32x2{work[rt * 2][r], work[rt * 2 + 1][r]});
        work[rt * 2][r] = v[0]; work[rt * 2 + 1][r] = v[1];
      }
  };
  auto epi_gelu_res = [&]() {    // bias already in acc init
    #pragma unroll
    for (int rt = 0; rt < 4; ++rt)
      #pragma unroll
      for (int r = 0; r < 4; ++r) {
        f32x2 v = gelu2(f32x2{work[rt * 2][r], work[rt * 2 + 1][r]})
                + f32x2{resid[rt * 2][r], resid[rt * 2 + 1][r]};
        resid[rt * 2][r] = v[0]; resid[rt * 2 + 1][r] = v[1];
        work[rt * 2][r] = v[0];  work[rt * 2 + 1][r] = v[1];
      }
  };

  for (int s = 0; s < 10; ++s) {
    const float* tw  = tvecs + s * 512;
    const float* tsk = tvecs + s * 512 + 256;
    f32x2 tcw = *(const f32x2*)(tw + colw);
    f32x2 tcs = *(const f32x2*)(tsk + colw);
    // skip -> resid (C init = tskip), y1 -> work (C init = tw1):
    // ONE lcond pass, two B's, merged epilogue adds x@bot only.
    mm_tile2_dual(Acond, wts + 2 * 65536 + wlane, wts + 1 * 65536 + wlane,
                  resid, work, tcs, tcw);
    epi_bot_dual();
    write_act(lact0);
    __syncthreads();                               // B1: y1 in lact0
    // h = gelu(y1 @ W2 + b2) + skip                -> lact1
    mm_tile2(A0, wts + 3 * 65536 + wlane, work, b2c);
    epi_gelu_res();
    write_act(lact1);     // != read buffer: no pre-barrier needed
    __syncthreads();                               // B2: h in lact1
    // 3 residual blocks: g1 lact1->lact0, g2 lact0->lact1
    for (int blk = 0; blk < 3; ++blk) {
      mm_tile2(A1, wts + (4 + blk) * 65536 + wlane, work, g1c[blk]);
      epi_gelu();
      write_act(lact0);
      __syncthreads();                             // g1 in lact0
      mm_tile2(A0, wts + (7 + blk) * 65536 + wlane, work, g2c[blk]);
      epi_gelu_res();
      write_act(lact1);
      __syncthreads();                             // g2 in lact1
    }
    // pred = h @ final_w + final_b via MFMA (waves 0,1: 32 rows each)
    if (wave < 2) {
      f32x4 pacc[4];
      mm_tile22(lact1 + (wave * 32 + l16) * KP + quad * 8,
                wts + 10 * 65536 + lane * 8, pacc, fbc);  // + final_b folded
      if (l16 < 2) {
        f32x4 sc = *(const f32x4*)(stepsc + s * 4);
        #pragma unroll
        for (int ct = 0; ct < 2; ++ct) {
          int col = l16 * 2 + ct;
          #pragma unroll
          for (int rt = 0; rt < 2; ++rt)
            #pragma unroll
            for (int r = 0; r < 4; ++r) {
              int row = wave * 32 + rt * 16 + quad * 4 + r;
              float accp = pacc[rt * 2 + ct][r];
              float xv = lx[row * 4 + col];
              xv = (xv - sc[1] * accp) * sc[0];
              xv = fmaf(sc[2],
                        noises[(size_t)s * nb * 4 + (size_t)(rowbase + row) * 4 + col],
                        xv);
              lx[row * 4 + col] = xv;   // readers only after B9
            }
        }
      }
    }
    __syncthreads();                               // B9: lx + lact1 reads done
  }
  if (tid < 256) {
    float xf = lx[tid];
    xf = fminf(1.0f, fmaxf(-1.0f, xf));
    out[rowbase * 4 + tid] = xf;
  }
}

// ---------------------------------------------------------------------------
extern "C" void kernel_launch(void* const* d_in, const int* in_sizes, int n_in,
                              void* d_out, int out_size, void* d_ws, size_t ws_size,
                              hipStream_t stream) {
  (void)n_in; (void)out_size; (void)ws_size;
  const float* features    = (const float*)d_in[0];
  const float* cond_w      = (const float*)d_in[1];
  const float* cond_b      = (const float*)d_in[2];
  const float* time_w      = (const float*)d_in[3];
  const float* time_b      = (const float*)d_in[4];
  const float* blk0_w1     = (const float*)d_in[5];
  const float* blk0_b1     = (const float*)d_in[6];
  const float* blk0_w2     = (const float*)d_in[7];
  const float* blk0_b2     = (const float*)d_in[8];
  const float* blk0_skip_w = (const float*)d_in[9];
  const float* blk0_skip_b = (const float*)d_in[10];
  const float* blks_w1     = (const float*)d_in[11];
  const float* blks_b1     = (const float*)d_in[12];
  const float* blks_w2     = (const float*)d_in[13];
  const float* blks_b2     = (const float*)d_in[14];
  const float* final_w     = (const float*)d_in[15];
  const float* final_b     = (const float*)d_in[16];

  const int nb = in_sizes[0] / 256;   // batch (32768)

  // workspace layout (bytes, 256-aligned)
  char* ws = (char*)d_ws;
  bf16_t* wts    = (bf16_t*)(ws + 0);        // (10*65536 + 8192) bf16 = 1,327,104 B
  float*  tvecs  = (float*)(ws + 1327104);   // 10 * 512 f32    = 20,480 B
  float*  stepsc = (float*)(ws + 1347584);   // 10 * 4 f32      (pad to 256)
  float*  x0w    = (float*)(ws + 1347840);   // nb*4 f32        = 524,288 B
  float*  noisew = (float*)(ws + 1872128);   // 10*nb*4 f32     = 5,242,880 B
  bf16_t* condw  = (bf16_t*)(ws + 7115008);  // nb*256 bf16     = 16,777,216 B

  wprep_kernel<<<2592, 256, 0, stream>>>(cond_w, blk0_w1, blk0_skip_w, blk0_w2,
                                         blks_w1, blks_w2, final_w, wts);
  prep_kernel<<<10, 256, 0, stream>>>(time_w, time_b, blk0_w1, blk0_b1,
                                      blk0_skip_w, blk0_skip_b, tvecs, stepsc);
  noise_kernel<<<(nb * 44 + 255) / 256, 256, 0, stream>>>(x0w, noisew, nb);
  cond_kernel<<<nb / MTILE, 256, 0, stream>>>(features, wts, cond_b, condw);
  fused_kernel<<<nb / MTILE, 512, 0, stream>>>(
      condw, wts, tvecs, stepsc, x0w, noisew,
      blk0_w1 + 512 * 256, blk0_skip_w + 512 * 256, blk0_b2,
      blks_b1, blks_b2, final_b, (float*)d_out, nb);
}

// Round 17
// 645.752 us; speedup vs baseline: 1.5119x; 1.1556x over previous
//
#include <hip/hip_runtime.h>
#include <stdint.h>
#include <stddef.h>

// ---------------------------------------------------------------------------
// DiffusionActionHead: fully fused 10-step DDPM sampler, bf16 MFMA.
//   B=32768, H=256, A=4, 10 inference steps.
//   1. wprep_kernel  : repack 10 weight matrices + final_w tile -> bf16 frags
//   2. prep_kernel   : per-step temb-derived col-vectors tw1/tskip + scalars
//   3. noise_kernel  : JAX threefry2x32, PARTITIONABLE counter scheme
//   4. cond_kernel   : cond = features @ cond_w + cond_b  (bf16 out)
//   5. fused_kernel  : 10 steps x 9 K=256 GEMMs per 64-row tile.
//      ROUND 15 RE-RESUBMIT (two consecutive GPU-acquisition timeouts;
//      hypothesis still untested. Source identical):
//      r14 = champion 718us fused, VALUBusy 51% still the bound;
//      GELU is the dominant VALU consumer at 128 gelu2/step/thread:
//        - gelu2: erf-rational (12 pk VALU + 4 trans) -> TANH-FORM via
//          sigmoid identity  x - x/(exp2(m)+1), m = x*(A + B*x^2)
//          (5 pk VALU + 4 trans). ~7 instr cut x 128/step/thread ~= 25%
//          of epilogue VALU. |tanh-gelu - erf-gelu| <= ~1e-3 << bf16
//          activation rounding 4e-3; pred errors damped ~10x by x-update
//          scale. Endpoints exact; exp2 saturates cleanly.
//        - prep_kernel keeps exact-erf gelu_f (one-time, tvecs bit-stable).
//        - everything else = r14 champion: MTILE=64, dual GEMM, dbuf lact
//          (9 barriers), bias-folded MFMA C init, hoisted constants,
//          pred-MFMA on waves 0,1, KP=272, (512,1) bounds.
// ---------------------------------------------------------------------------

typedef __bf16 bf16_t;
typedef __bf16 bf16x8 __attribute__((ext_vector_type(8)));
typedef __bf16 bf16x4 __attribute__((ext_vector_type(4)));
typedef __bf16 bf16x2 __attribute__((ext_vector_type(2)));
typedef float  f32x4  __attribute__((ext_vector_type(4)));
typedef float  f32x2  __attribute__((ext_vector_type(2)));

constexpr int KP    = 272;   // LDS row stride in bf16 elems (256 + 16 pad)
constexpr int MTILE = 64;    // rows per workgroup

// ---------------- packed f32x2 helpers -------------------------------------
__device__ __forceinline__ f32x2 bc2(float v) { return f32x2{v, v}; }
__device__ __forceinline__ f32x2 fma2(f32x2 a, f32x2 b, f32x2 c) {
#if __has_builtin(__builtin_elementwise_fma)
  return __builtin_elementwise_fma(a, b, c);
#else
  return f32x2{fmaf(a[0], b[0], c[0]), fmaf(a[1], b[1], c[1])};
#endif
}

// ---------------- exact-erf GELU (A&S 7.1.26) for prep_kernel ---------------
__device__ __forceinline__ float gelu_f(float x) {
  float z  = 0.70710678f * x;
  float az = fabsf(z);
  float t  = __builtin_amdgcn_rcpf(fmaf(0.3275911f, az, 1.0f));
  float e  = __expf(-az * az);
  float p  = fmaf(1.061405429f, t, -1.453152027f);
  p = fmaf(p, t, 1.421413741f);
  p = fmaf(p, t, -0.284496736f);
  p = fmaf(p, t, 0.254829592f);
  float er = fmaf(-(p * t), e, 1.0f);   // erf(|z|)
  er = copysignf(er, z);
  return 0.5f * x * (1.0f + er);
}
// packed tanh-form GELU via sigmoid identity:
//   gelu(x) ~= x * sigmoid(1.5957691x + 0.0713548x^3)
//            = x - x / (exp2(m) + 1),  m = x*(A + B*x^2)
//   A = 2*0.7978845608*log2(e) = 2.30211784, B = A*0.044715 = 0.10293942
// |err vs exact erf-gelu| <= ~1e-3, far below bf16 activation rounding.
__device__ __forceinline__ f32x2 gelu2(f32x2 x) {
  f32x2 x2 = x * x;
  f32x2 p  = fma2(bc2(0.10293942f), x2, bc2(2.30211784f));
  f32x2 m  = x * p;
  f32x2 e;
  e[0] = __builtin_amdgcn_exp2f(m[0]);
  e[1] = __builtin_amdgcn_exp2f(m[1]);
  f32x2 d  = e + bc2(1.0f);
  f32x2 r;
  r[0] = __builtin_amdgcn_rcpf(d[0]);
  r[1] = __builtin_amdgcn_rcpf(d[1]);
  return fma2(-x, r, x);     // x - x/(e^(2u)+1) = x*sigmoid(2u)
}

// ---------------- JAX threefry2x32 (20 rounds) ------------------------------
#define TFR(a) x0 += x1; x1 = (x1 << (a)) | (x1 >> (32 - (a))); x1 ^= x0;
__device__ __forceinline__ void tf2(uint32_t k0, uint32_t k1,
                                    uint32_t x0, uint32_t x1,
                                    uint32_t& o0, uint32_t& o1) {
  uint32_t k2 = k0 ^ k1 ^ 0x1BD11BDAu;
  x0 += k0; x1 += k1;
  TFR(13) TFR(15) TFR(26) TFR(6)
  x0 += k1; x1 += k2 + 1u;
  TFR(17) TFR(29) TFR(16) TFR(24)
  x0 += k2; x1 += k0 + 2u;
  TFR(13) TFR(15) TFR(26) TFR(6)
  x0 += k0; x1 += k1 + 3u;
  TFR(17) TFR(29) TFR(16) TFR(24)
  x0 += k1; x1 += k2 + 4u;
  TFR(13) TFR(15) TFR(26) TFR(6)
  x0 += k2; x1 += k0 + 5u;
  o0 = x0; o1 = x1;
}
#undef TFR

// uniform bits -> N(0,1) exactly like jax.random.normal (XLA erfinv poly)
__device__ __forceinline__ float nrm_from_bits(uint32_t bits) {
  float f = __uint_as_float((bits >> 9) | 0x3f800000u) - 1.0f;  // [0,1)
  const float lo = -0.99999994f;                                 // nextafter(-1,0)
  float u = fmaxf(lo, __fadd_rn(__fmul_rn(f, 2.0f), lo));        // (hi-lo)==2.0f in f32
  float w = -log1pf(-__fmul_rn(u, u));
  float p;
  if (w < 5.0f) {
    float ww = w - 2.5f;
    p = 2.81022636e-08f;
    p = fmaf(p, ww, 3.43273939e-07f);
    p = fmaf(p, ww, -3.5233877e-06f);
    p = fmaf(p, ww, -4.39150654e-06f);
    p = fmaf(p, ww, 0.00021858087f);
    p = fmaf(p, ww, -0.00125372503f);
    p = fmaf(p, ww, -0.00417768164f);
    p = fmaf(p, ww, 0.246640727f);
    p = fmaf(p, ww, 1.50140941f);
  } else {
    float ww = sqrtf(w) - 3.0f;
    p = -0.000200214257f;
    p = fmaf(p, ww, 0.000100950558f);
    p = fmaf(p, ww, 0.00134934322f);
    p = fmaf(p, ww, -0.00367342844f);
    p = fmaf(p, ww, 0.00573950773f);
    p = fmaf(p, ww, -0.0076224613f);
    p = fmaf(p, ww, 0.00943887047f);
    p = fmaf(p, ww, 1.00167406f);
    p = fmaf(p, ww, 2.83297682f);
  }
  return 1.41421354f * (p * u);   // sqrt(2) * erfinv(u)
}

// ---------------- 64x64 MFMA tile (4 ntiles/wave, cond_kernel) -------------
__device__ __forceinline__ void mm_tile(const bf16_t* __restrict__ A,
                                        const bf16_t* __restrict__ Wp,
                                        f32x4 acc[16]) {
  #pragma unroll
  for (int i = 0; i < 16; ++i) acc[i] = f32x4{0.f, 0.f, 0.f, 0.f};
  #pragma unroll 2
  for (int kc = 0; kc < 8; ++kc) {
    bf16x8 a[4], b[4];
    #pragma unroll
    for (int rt = 0; rt < 4; ++rt)
      a[rt] = *(const bf16x8*)(A + rt * 16 * KP + kc * 32);
    #pragma unroll
    for (int ct = 0; ct < 4; ++ct)
      b[ct] = *(const bf16x8*)(Wp + ct * 4096 + kc * 512);
    #pragma unroll
    for (int rt = 0; rt < 4; ++rt)
      #pragma unroll
      for (int ct = 0; ct < 4; ++ct)
        acc[rt * 4 + ct] =
            __builtin_amdgcn_mfma_f32_16x16x32_bf16(a[rt], b[ct], acc[rt * 4 + ct], 0, 0, 0);
  }
}

// ---------------- 64x32 MFMA tile, bias-folded C init ----------------------
// acc[rt*2+ct] lanes = 4 rows of column (colw+ct) -> init with ini[ct].
__device__ __forceinline__ void mm_tile2(const bf16_t* __restrict__ A,
                                         const bf16_t* __restrict__ Wp,
                                         f32x4 acc[8], f32x2 ini) {
  #pragma unroll
  for (int rt = 0; rt < 4; ++rt)
    #pragma unroll
    for (int ct = 0; ct < 2; ++ct)
      acc[rt * 2 + ct] = f32x4{ini[ct], ini[ct], ini[ct], ini[ct]};
  #pragma unroll 2
  for (int kc = 0; kc < 8; ++kc) {
    bf16x8 a[4], b[2];
    #pragma unroll
    for (int rt = 0; rt < 4; ++rt)
      a[rt] = *(const bf16x8*)(A + rt * 16 * KP + kc * 32);
    #pragma unroll
    for (int ct = 0; ct < 2; ++ct)
      b[ct] = *(const bf16x8*)(Wp + ct * 4096 + kc * 512);
    #pragma unroll
    for (int rt = 0; rt < 4; ++rt)
      #pragma unroll
      for (int ct = 0; ct < 2; ++ct)
        acc[rt * 2 + ct] =
            __builtin_amdgcn_mfma_f32_16x16x32_bf16(a[rt], b[ct], acc[rt * 2 + ct], 0, 0, 0);
  }
}

// 32x32 MFMA tile for the pred GEMM (rows pre-offset in A), bias-folded
__device__ __forceinline__ void mm_tile22(const bf16_t* __restrict__ A,
                                          const bf16_t* __restrict__ Wp,
                                          f32x4 acc[4], f32x2 ini) {
  #pragma unroll
  for (int rt = 0; rt < 2; ++rt)
    #pragma unroll
    for (int ct = 0; ct < 2; ++ct)
      acc[rt * 2 + ct] = f32x4{ini[ct], ini[ct], ini[ct], ini[ct]};
  #pragma unroll 2
  for (int kc = 0; kc < 8; ++kc) {
    bf16x8 a[2], b[2];
    #pragma unroll
    for (int rt = 0; rt < 2; ++rt)
      a[rt] = *(const bf16x8*)(A + rt * 16 * KP + kc * 32);
    #pragma unroll
    for (int ct = 0; ct < 2; ++ct)
      b[ct] = *(const bf16x8*)(Wp + ct * 4096 + kc * 512);
    #pragma unroll
    for (int rt = 0; rt < 2; ++rt)
      #pragma unroll
      for (int ct = 0; ct < 2; ++ct)
        acc[rt * 2 + ct] =
            __builtin_amdgcn_mfma_f32_16x16x32_bf16(a[rt], b[ct], acc[rt * 2 + ct], 0, 0, 0);
  }
}

// Dual: one A pass (lcond) feeds TWO B's -> skip (acc1) + y1 (acc2),
// each with its own per-column C init (tskip / tw1).
__device__ __forceinline__ void mm_tile2_dual(const bf16_t* __restrict__ A,
                                              const bf16_t* __restrict__ W1,
                                              const bf16_t* __restrict__ W2,
                                              f32x4 acc1[8], f32x4 acc2[8],
                                              f32x2 ini1, f32x2 ini2) {
  #pragma unroll
  for (int rt = 0; rt < 4; ++rt)
    #pragma unroll
    for (int ct = 0; ct < 2; ++ct) {
      acc1[rt * 2 + ct] = f32x4{ini1[ct], ini1[ct], ini1[ct], ini1[ct]};
      acc2[rt * 2 + ct] = f32x4{ini2[ct], ini2[ct], ini2[ct], ini2[ct]};
    }
  #pragma unroll 2
  for (int kc = 0; kc < 8; ++kc) {
    bf16x8 a[4];
    #pragma unroll
    for (int rt = 0; rt < 4; ++rt)
      a[rt] = *(const bf16x8*)(A + rt * 16 * KP + kc * 32);
    #pragma unroll
    for (int ct = 0; ct < 2; ++ct) {
      bf16x8 b = *(const bf16x8*)(W1 + ct * 4096 + kc * 512);
      #pragma unroll
      for (int rt = 0; rt < 4; ++rt)
        acc1[rt * 2 + ct] =
            __builtin_amdgcn_mfma_f32_16x16x32_bf16(a[rt], b, acc1[rt * 2 + ct], 0, 0, 0);
    }
    #pragma unroll
    for (int ct = 0; ct < 2; ++ct) {
      bf16x8 b = *(const bf16x8*)(W2 + ct * 4096 + kc * 512);
      #pragma unroll
      for (int rt = 0; rt < 4; ++rt)
        acc2[rt * 2 + ct] =
            __builtin_amdgcn_mfma_f32_16x16x32_bf16(a[rt], b, acc2[rt * 2 + ct], 0, 0, 0);
    }
  }
}

// ---------------- kernel 1: weight repack ----------------------------------
// dst element e = [m][nt][kc][lane][j]; value = src_m[k*256 + n],
// COLUMN REMAP: n = (nt>>1)*32 + (lane&15)*2 + (nt&1)
// m==10 (compact): final_w 256x4 zero-padded; col n<4 only for l16<2.
__global__ void wprep_kernel(const float* __restrict__ condw,
                             const float* __restrict__ w1,
                             const float* __restrict__ skw,
                             const float* __restrict__ w2,
                             const float* __restrict__ bw1,
                             const float* __restrict__ bw2,
                             const float* __restrict__ fw,
                             bf16_t* __restrict__ wts) {
  int e = blockIdx.x * 256 + threadIdx.x;
  int m = e >> 16;
  int r = e & 65535;
  int nt = r >> 12, kc = (r >> 9) & 7, lane = (r >> 3) & 63, j = r & 7;
  int n = (nt >> 1) * 32 + (lane & 15) * 2 + (nt & 1);
  int k = kc * 32 + (lane >> 4) * 8 + j;
  if (m == 10) {                               // compact final_w tile
    wts[e] = (n < 4) ? (bf16_t)fw[k * 4 + n] : (bf16_t)0.f;
    return;
  }
  const float* src;
  if      (m == 0) src = condw;
  else if (m == 1) src = w1;                    // blk0_w1 rows 0..255 (cond part)
  else if (m == 2) src = skw;                   // blk0_skip_w rows 0..255
  else if (m == 3) src = w2;                    // blk0_w2
  else if (m <= 6) src = bw1 + (m - 4) * 65536; // blks_w1[i]
  else             src = bw2 + (m - 7) * 65536; // blks_w2[i]
  wts[e] = (bf16_t)src[k * 256 + n];
}

// ---------------- kernel 2: per-step vectors + scalars ---------------------
__global__ void prep_kernel(const float* __restrict__ time_w,
                            const float* __restrict__ time_b,
                            const float* __restrict__ w1,
                            const float* __restrict__ b1,
                            const float* __restrict__ skw,
                            const float* __restrict__ skb,
                            float* __restrict__ tvecs,
                            float* __restrict__ stepsc) {
  int s = blockIdx.x;          // 0..9, t = 90 - 10*s
  int j = threadIdx.x;         // 0..255
  int t = 90 - s * 10;
  float tval = (float)t;
  __shared__ float emb[256];
  __shared__ float temb[256];
  if (j < 128) {
    float freq = expf((float)j * -0.07252236513366287f);  // -ln(1e4)/127
    float e = tval * freq;
    emb[j] = sinf(e);
    emb[j + 128] = cosf(e);
  }
  __syncthreads();
  float a = time_b[j];
  for (int k = 0; k < 256; ++k) a = fmaf(emb[k], time_w[k * 256 + j], a);
  temb[j] = gelu_f(a);
  __syncthreads();
  float v1 = b1[j], v2 = skb[j];
  for (int k = 0; k < 256; ++k) {
    float tk = temb[k];
    v1 = fmaf(tk, w1[(256 + k) * 256 + j], v1);    // blk0_w1 rows 256..511
    v2 = fmaf(tk, skw[(256 + k) * 256 + j], v2);   // blk0_skip_w rows 256..511
  }
  tvecs[s * 512 + j] = v1;         // tw1 (includes b1)
  tvecs[s * 512 + 256 + j] = v2;   // tskip (includes skip_b)
  if (j == 0) {
    float step = (0.02f - 1e-4f) / 99.0f;
    float acp = 1.0f, beta = 0.0f;
    for (int i = 0; i <= t; ++i) {
      beta = fmaf((float)i, step, 1e-4f);
      acp *= (1.0f - beta);
    }
    stepsc[s * 4 + 0] = 1.0f / sqrtf(1.0f - beta);   // 1/sqrt(alpha)
    stepsc[s * 4 + 1] = beta / sqrtf(1.0f - acp);    // b/sqrt(1-acp)
    stepsc[s * 4 + 2] = (t > 0) ? sqrtf(beta) : 0.0f;
    stepsc[s * 4 + 3] = 0.0f;
  }
}

// ---------------- kernel 3: x0 + noises via PARTITIONABLE threefry ---------
__global__ void noise_kernel(float* __restrict__ xout, float* __restrict__ nout, int nb) {
  int gid = blockIdx.x * 256 + threadIdx.x;
  int nx = nb * 4;     // 131072 x0 elements
  int nn = nb * 40;    // 1310720 noise elements
  uint32_t k0, k1, o0, o1;
  if (gid < nx) {
    tf2(0u, 42u, 0u, 999u, k0, k1);                 // fold_in(key(42), 999)
    tf2(k0, k1, 0u, (uint32_t)gid, o0, o1);
    xout[gid] = nrm_from_bits(o0 ^ o1);
  } else if (gid < nx + nn) {
    int i = gid - nx;
    tf2(0u, 42u, 0u, 7u, k0, k1);                   // fold_in(key(42), 7)
    tf2(k0, k1, 0u, (uint32_t)i, o0, o1);
    nout[i] = nrm_from_bits(o0 ^ o1);
  }
}

// ---------------- kernel 4: cond = features @ cond_w + cond_b --------------
__global__ __launch_bounds__(256, 2) void cond_kernel(
    const float* __restrict__ feat, const bf16_t* __restrict__ wts,
    const float* __restrict__ condb, bf16_t* __restrict__ condg) {
  __shared__ __align__(16) bf16_t la[MTILE * KP];
  const int tid = threadIdx.x;
  const int wave = tid >> 6, lane = tid & 63, quad = lane >> 4, l16 = lane & 15;
  const int rowbase = blockIdx.x * MTILE;
  for (int it = 0; it < 16; ++it) {
    int e = (it * 256 + tid) * 4;
    int rr = e >> 8, c = e & 255;
    f32x4 v = *(const f32x4*)(feat + (size_t)(rowbase + rr) * 256 + c);
    bf16x4 bv;
    bv[0] = (bf16_t)v[0]; bv[1] = (bf16_t)v[1];
    bv[2] = (bf16_t)v[2]; bv[3] = (bf16_t)v[3];
    *(bf16x4*)(la + rr * KP + c) = bv;
  }
  __syncthreads();
  f32x4 acc[16];
  mm_tile(la + l16 * KP + quad * 8, wts + wave * 16384 + lane * 8, acc);
  const int c0 = wave * 64 + l16 * 2;            // ct 0,1 -> c0, ct 2,3 -> c0+32
  f32x2 b0 = *(const f32x2*)(condb + c0);
  f32x2 b1 = *(const f32x2*)(condb + c0 + 32);
  #pragma unroll
  for (int rt = 0; rt < 4; ++rt)
    #pragma unroll
    for (int r = 0; r < 4; ++r) {
      int row = rt * 16 + quad * 4 + r;
      bf16x2 p0, p1;
      p0[0] = (bf16_t)(acc[rt * 4 + 0][r] + b0[0]);
      p0[1] = (bf16_t)(acc[rt * 4 + 1][r] + b0[1]);
      p1[0] = (bf16_t)(acc[rt * 4 + 2][r] + b1[0]);
      p1[1] = (bf16_t)(acc[rt * 4 + 3][r] + b1[1]);
      *(bf16x2*)(condg + (size_t)(rowbase + row) * 256 + c0) = p0;
      *(bf16x2*)(condg + (size_t)(rowbase + row) * 256 + c0 + 32) = p1;
    }
}

// ---------------- kernel 5: fused 10-step sampler (512 thr / 8 waves) ------
// r14 champion structure + tanh-form packed GELU.
__global__ __launch_bounds__(512, 1) void fused_kernel(
    const bf16_t* __restrict__ condg, const bf16_t* __restrict__ wts,
    const float* __restrict__ tvecs, const float* __restrict__ stepsc,
    const float* __restrict__ x0w, const float* __restrict__ noises,
    const float* __restrict__ w1bot, const float* __restrict__ skipbot,
    const float* __restrict__ b2v, const float* __restrict__ blksb1,
    const float* __restrict__ blksb2,
    const float* __restrict__ finalb, float* __restrict__ out, int nb) {
  __shared__ __align__(16) bf16_t lcond[MTILE * KP];
  __shared__ __align__(16) bf16_t lact0[MTILE * KP];   // double-buffered act
  __shared__ __align__(16) bf16_t lact1[MTILE * KP];
  __shared__ __align__(16) float  lx[MTILE * 4];
  const int tid = threadIdx.x;
  const int wave = tid >> 6, lane = tid & 63, quad = lane >> 4, l16 = lane & 15;
  const int rowbase = blockIdx.x * MTILE;

  // stage cond tile (persists all 10 steps) + x0
  {
    int rr = tid >> 3, c = (tid & 7) * 32;
    const bf16_t* src = condg + (size_t)(rowbase + rr) * 256 + c;
    bf16_t* dst = lcond + rr * KP + c;
    #pragma unroll
    for (int j = 0; j < 4; ++j)
      *(bf16x8*)(dst + j * 8) = *(const bf16x8*)(src + j * 8);
  }
  if (tid < 256) lx[tid] = x0w[rowbase * 4 + tid];
  __syncthreads();

  const bf16_t* Acond = lcond + l16 * KP + quad * 8;
  const bf16_t* A0    = lact0 + l16 * KP + quad * 8;
  const bf16_t* A1    = lact1 + l16 * KP + quad * 8;
  const int colw = wave * 32 + l16 * 2;          // 2 consecutive cols/lane
  const int wlane = wave * 8192 + lane * 8;
  f32x4 resid[8], work[8];

  // step-invariant per-column constants, hoisted to registers
  const f32x2 ss0 = *(const f32x2*)(skipbot + colw);
  const f32x2 ss1 = *(const f32x2*)(skipbot + 256 + colw);
  const f32x2 ss2 = *(const f32x2*)(skipbot + 512 + colw);
  const f32x2 ss3 = *(const f32x2*)(skipbot + 768 + colw);
  const f32x2 sw0 = *(const f32x2*)(w1bot + colw);
  const f32x2 sw1 = *(const f32x2*)(w1bot + 256 + colw);
  const f32x2 sw2 = *(const f32x2*)(w1bot + 512 + colw);
  const f32x2 sw3 = *(const f32x2*)(w1bot + 768 + colw);
  const f32x2 b2c = *(const f32x2*)(b2v + colw);
  f32x2 g1c[3], g2c[3];
  #pragma unroll
  for (int blk = 0; blk < 3; ++blk) {
    g1c[blk] = *(const f32x2*)(blksb1 + blk * 256 + colw);
    g2c[blk] = *(const f32x2*)(blksb2 + blk * 256 + colw);
  }
  f32x2 fbc;
  {
    int bi = (l16 < 2) ? (int)(l16 * 2) : 0;   // valid lanes only; rest unused
    fbc[0] = finalb[bi]; fbc[1] = finalb[bi + 1];
  }

  // pack lane's 2 consecutive cols -> one ds_write_b32 per (rt,r)
  auto write_act = [&](bf16_t* dst) {
    #pragma unroll
    for (int rt = 0; rt < 4; ++rt)
      #pragma unroll
      for (int r = 0; r < 4; ++r) {
        bf16x2 pv;
        pv[0] = (bf16_t)work[rt * 2 + 0][r];
        pv[1] = (bf16_t)work[rt * 2 + 1][r];
        *(bf16x2*)(dst + (rt * 16 + quad * 4 + r) * KP + colw) = pv;
      }
  };
  // merged K=516-factorized epilogue: x@bot add (tvec already in acc init);
  // skip stays linear in resid, y1 gets gelu into work.
  auto epi_bot_dual = [&]() {
    #pragma unroll
    for (int rt = 0; rt < 4; ++rt)
      #pragma unroll
      for (int r = 0; r < 4; ++r) {
        f32x4 xv = *(const f32x4*)(lx + (rt * 16 + quad * 4 + r) * 4);
        f32x2 vs = f32x2{resid[rt * 2][r], resid[rt * 2 + 1][r]};
        vs = fma2(bc2(xv[0]), ss0, vs);
        vs = fma2(bc2(xv[1]), ss1, vs);
        vs = fma2(bc2(xv[2]), ss2, vs);
        vs = fma2(bc2(xv[3]), ss3, vs);
        resid[rt * 2][r] = vs[0]; resid[rt * 2 + 1][r] = vs[1];
        f32x2 vw = f32x2{work[rt * 2][r], work[rt * 2 + 1][r]};
        vw = fma2(bc2(xv[0]), sw0, vw);
        vw = fma2(bc2(xv[1]), sw1, vw);
        vw = fma2(bc2(xv[2]), sw2, vw);
        vw = fma2(bc2(xv[3]), sw3, vw);
        vw = gelu2(vw);
        work[rt * 2][r] = vw[0]; work[rt * 2 + 1][r] = vw[1];
      }
  };
  auto epi_gelu = [&]() {        // bias already in acc init
    #pragma unroll
    for (int rt = 0; rt < 4; ++rt)
      #pragma unroll
      for (int r = 0; r < 4; ++r) {
        f32x2 v = gelu2(f32x2{work[rt * 2][r], work[rt * 2 + 1][r]});
        work[rt * 2][r] = v[0]; work[rt * 2 + 1][r] = v[1];
      }
  };
  auto epi_gelu_res = [&]() {    // bias already in acc init
    #pragma unroll
    for (int rt = 0; rt < 4; ++rt)
      #pragma unroll
      for (int r = 0; r < 4; ++r) {
        f32x2 v = gelu2(f32x2{work[rt * 2][r], work[rt * 2 + 1][r]})
                + f32x2{resid[rt * 2][r], resid[rt * 2 + 1][r]};
        resid[rt * 2][r] = v[0]; resid[rt * 2 + 1][r] = v[1];
        work[rt * 2][r] = v[0];  work[rt * 2 + 1][r] = v[1];
      }
  };

  for (int s = 0; s < 10; ++s) {
    const float* tw  = tvecs + s * 512;
    const float* tsk = tvecs + s * 512 + 256;
    f32x2 tcw = *(const f32x2*)(tw + colw);
    f32x2 tcs = *(const f32x2*)(tsk + colw);
    // skip -> resid (C init = tskip), y1 -> work (C init = tw1):
    // ONE lcond pass, two B's, merged epilogue adds x@bot only.
    mm_tile2_dual(Acond, wts + 2 * 65536 + wlane, wts + 1 * 65536 + wlane,
                  resid, work, tcs, tcw);
    epi_bot_dual();
    write_act(lact0);
    __syncthreads();                               // B1: y1 in lact0
    // h = gelu(y1 @ W2 + b2) + skip                -> lact1
    mm_tile2(A0, wts + 3 * 65536 + wlane, work, b2c);
    epi_gelu_res();
    write_act(lact1);     // != read buffer: no pre-barrier needed
    __syncthreads();                               // B2: h in lact1
    // 3 residual blocks: g1 lact1->lact0, g2 lact0->lact1
    for (int blk = 0; blk < 3; ++blk) {
      mm_tile2(A1, wts + (4 + blk) * 65536 + wlane, work, g1c[blk]);
      epi_gelu();
      write_act(lact0);
      __syncthreads();                             // g1 in lact0
      mm_tile2(A0, wts + (7 + blk) * 65536 + wlane, work, g2c[blk]);
      epi_gelu_res();
      write_act(lact1);
      __syncthreads();                             // g2 in lact1
    }
    // pred = h @ final_w + final_b via MFMA (waves 0,1: 32 rows each)
    if (wave < 2) {
      f32x4 pacc[4];
      mm_tile22(lact1 + (wave * 32 + l16) * KP + quad * 8,
                wts + 10 * 65536 + lane * 8, pacc, fbc);  // + final_b folded
      if (l16 < 2) {
        f32x4 sc = *(const f32x4*)(stepsc + s * 4);
        #pragma unroll
        for (int ct = 0; ct < 2; ++ct) {
          int col = l16 * 2 + ct;
          #pragma unroll
          for (int rt = 0; rt < 2; ++rt)
            #pragma unroll
            for (int r = 0; r < 4; ++r) {
              int row = wave * 32 + rt * 16 + quad * 4 + r;
              float accp = pacc[rt * 2 + ct][r];
              float xv = lx[row * 4 + col];
              xv = (xv - sc[1] * accp) * sc[0];
              xv = fmaf(sc[2],
                        noises[(size_t)s * nb * 4 + (size_t)(rowbase + row) * 4 + col],
                        xv);
              lx[row * 4 + col] = xv;   // readers only after B9
            }
        }
      }
    }
    __syncthreads();                               // B9: lx + lact1 reads done
  }
  if (tid < 256) {
    float xf = lx[tid];
    xf = fminf(1.0f, fmaxf(-1.0f, xf));
    out[rowbase * 4 + tid] = xf;
  }
}

// ---------------------------------------------------------------------------
extern "C" void kernel_launch(void* const* d_in, const int* in_sizes, int n_in,
                              void* d_out, int out_size, void* d_ws, size_t ws_size,
                              hipStream_t stream) {
  (void)n_in; (void)out_size; (void)ws_size;
  const float* features    = (const float*)d_in[0];
  const float* cond_w      = (const float*)d_in[1];
  const float* cond_b      = (const float*)d_in[2];
  const float* time_w      = (const float*)d_in[3];
  const float* time_b      = (const float*)d_in[4];
  const float* blk0_w1     = (const float*)d_in[5];
  const float* blk0_b1     = (const float*)d_in[6];
  const float* blk0_w2     = (const float*)d_in[7];
  const float* blk0_b2     = (const float*)d_in[8];
  const float* blk0_skip_w = (const float*)d_in[9];
  const float* blk0_skip_b = (const float*)d_in[10];
  const float* blks_w1     = (const float*)d_in[11];
  const float* blks_b1     = (const float*)d_in[12];
  const float* blks_w2     = (const float*)d_in[13];
  const float* blks_b2     = (const float*)d_in[14];
  const float* final_w     = (const float*)d_in[15];
  const float* final_b     = (const float*)d_in[16];

  const int nb = in_sizes[0] / 256;   // batch (32768)

  // workspace layout (bytes, 256-aligned)
  char* ws = (char*)d_ws;
  bf16_t* wts    = (bf16_t*)(ws + 0);        // (10*65536 + 8192) bf16 = 1,327,104 B
  float*  tvecs  = (float*)(ws + 1327104);   // 10 * 512 f32    = 20,480 B
  float*  stepsc = (float*)(ws + 1347584);   // 10 * 4 f32      (pad to 256)
  float*  x0w    = (float*)(ws + 1347840);   // nb*4 f32        = 524,288 B
  float*  noisew = (float*)(ws + 1872128);   // 10*nb*4 f32     = 5,242,880 B
  bf16_t* condw  = (bf16_t*)(ws + 7115008);  // nb*256 bf16     = 16,777,216 B

  wprep_kernel<<<2592, 256, 0, stream>>>(cond_w, blk0_w1, blk0_skip_w, blk0_w2,
                                         blks_w1, blks_w2, final_w, wts);
  prep_kernel<<<10, 256, 0, stream>>>(time_w, time_b, blk0_w1, blk0_b1,
                                      blk0_skip_w, blk0_skip_b, tvecs, stepsc);
  noise_kernel<<<(nb * 44 + 255) / 256, 256, 0, stream>>>(x0w, noisew, nb);
  cond_kernel<<<nb / MTILE, 256, 0, stream>>>(features, wts, cond_b, condw);
  fused_kernel<<<nb / MTILE, 512, 0, stream>>>(
      condw, wts, tvecs, stepsc, x0w, noisew,
      blk0_w1 + 512 * 256, blk0_skip_w + 512 * 256, blk0_b2,
      blks_b1, blks_b2, final_b, (float*)d_out, nb);
}

// Round 18
// 628.946 us; speedup vs baseline: 1.5523x; 1.0267x over previous
//
#include <hip/hip_runtime.h>
#include <stdint.h>
#include <stddef.h>

// ---------------------------------------------------------------------------
// DiffusionActionHead: fully fused 10-step DDPM sampler, bf16 MFMA.
//   B=32768, H=256, A=4, 10 inference steps.
//   1. wprep_kernel  : repack 10 weight matrices + fw tile + 2 compact bot
//                      fragment tiles (x@bot fold) -> bf16 MFMA-B frags
//   2. prep_kernel   : per-step temb-derived col-vectors tw1/tskip + scalars
//   3. noise_kernel  : JAX threefry2x32, PARTITIONABLE counter scheme
//   4. cond_kernel   : cond = features @ cond_w + cond_b  (bf16 out)
//   5. fused_kernel  : 10 steps x 9 K-extended GEMMs per 64-row tile.
//      ROUND 18 (r17 = champion 611us fused via tanh-gelu; VALUBusy 43%,
//      MfmaUtil 29%. Largest remaining epilogue block = epi_bot_dual's
//      rank-4 update x[64x4]@bot[4x256]: 16 lx-loads + 128 pk-fma/thr/step):
//        - FOLD x@bot INTO THE MFMA K-DIM: dual GEMM gets one extra K=32
//          block. A = x as bf16 in lxb[64][32] (cols 4..31 zero, 4KB LDS);
//          B = bot rows in two compact zero-padded fragment tiles
//          (step-invariant, built by wprep). +16 MFMA/thr/step on the
//          29%-busy matrix pipe; epi_bot_dual collapses to a gelu pass
//          (resid = MFMA output directly); 8 hoisted const regs freed.
//        - pred phase writes lxb (bf16 of new x) alongside lx; B9 barrier
//          makes it visible to the next step's dual. Init covers s=0.
//        - numerics: x enters GEMM as bf16 (~0.2% rel) on a ~0.2-magnitude
//          term -> ~4e-4 abs, inside the accepted 0.0039 envelope.
//        - everything else = r17 champion: MTILE=64, dual GEMM, dbuf lact
//          (9 barriers), bias-folded C init, tanh-gelu, pred-MFMA, KP=272.
// ---------------------------------------------------------------------------

typedef __bf16 bf16_t;
typedef __bf16 bf16x8 __attribute__((ext_vector_type(8)));
typedef __bf16 bf16x4 __attribute__((ext_vector_type(4)));
typedef __bf16 bf16x2 __attribute__((ext_vector_type(2)));
typedef float  f32x4  __attribute__((ext_vector_type(4)));
typedef float  f32x2  __attribute__((ext_vector_type(2)));

constexpr int KP    = 272;   // LDS row stride in bf16 elems (256 + 16 pad)
constexpr int MTILE = 64;    // rows per workgroup

// wts layout (bf16 elems): tiles 0..9 full (65536 each), tile10 fw (8192),
// tile11 skipbot-frag (8192), tile12 w1bot-frag (8192). total 679936.
constexpr int WT_FW  = 10 * 65536;            // 655360
constexpr int WT_BS  = WT_FW + 8192;          // 663552 (skipbot frag)
constexpr int WT_BW  = WT_BS + 8192;          // 671744 (w1bot frag)
constexpr int WT_TOT = WT_BW + 8192;          // 679936

// ---------------- packed f32x2 helpers -------------------------------------
__device__ __forceinline__ f32x2 bc2(float v) { return f32x2{v, v}; }
__device__ __forceinline__ f32x2 fma2(f32x2 a, f32x2 b, f32x2 c) {
#if __has_builtin(__builtin_elementwise_fma)
  return __builtin_elementwise_fma(a, b, c);
#else
  return f32x2{fmaf(a[0], b[0], c[0]), fmaf(a[1], b[1], c[1])};
#endif
}

// ---------------- exact-erf GELU (A&S 7.1.26) for prep_kernel ---------------
__device__ __forceinline__ float gelu_f(float x) {
  float z  = 0.70710678f * x;
  float az = fabsf(z);
  float t  = __builtin_amdgcn_rcpf(fmaf(0.3275911f, az, 1.0f));
  float e  = __expf(-az * az);
  float p  = fmaf(1.061405429f, t, -1.453152027f);
  p = fmaf(p, t, 1.421413741f);
  p = fmaf(p, t, -0.284496736f);
  p = fmaf(p, t, 0.254829592f);
  float er = fmaf(-(p * t), e, 1.0f);   // erf(|z|)
  er = copysignf(er, z);
  return 0.5f * x * (1.0f + er);
}
// packed tanh-form GELU via sigmoid identity (r17-verified):
//   gelu(x) = x - x / (exp2(m) + 1),  m = x*(A + B*x^2)
//   A = 2*0.7978845608*log2(e) = 2.30211784, B = A*0.044715 = 0.10293942
__device__ __forceinline__ f32x2 gelu2(f32x2 x) {
  f32x2 x2 = x * x;
  f32x2 p  = fma2(bc2(0.10293942f), x2, bc2(2.30211784f));
  f32x2 m  = x * p;
  f32x2 e;
  e[0] = __builtin_amdgcn_exp2f(m[0]);
  e[1] = __builtin_amdgcn_exp2f(m[1]);
  f32x2 d  = e + bc2(1.0f);
  f32x2 r;
  r[0] = __builtin_amdgcn_rcpf(d[0]);
  r[1] = __builtin_amdgcn_rcpf(d[1]);
  return fma2(-x, r, x);     // x * sigmoid(2u)
}

// ---------------- JAX threefry2x32 (20 rounds) ------------------------------
#define TFR(a) x0 += x1; x1 = (x1 << (a)) | (x1 >> (32 - (a))); x1 ^= x0;
__device__ __forceinline__ void tf2(uint32_t k0, uint32_t k1,
                                    uint32_t x0, uint32_t x1,
                                    uint32_t& o0, uint32_t& o1) {
  uint32_t k2 = k0 ^ k1 ^ 0x1BD11BDAu;
  x0 += k0; x1 += k1;
  TFR(13) TFR(15) TFR(26) TFR(6)
  x0 += k1; x1 += k2 + 1u;
  TFR(17) TFR(29) TFR(16) TFR(24)
  x0 += k2; x1 += k0 + 2u;
  TFR(13) TFR(15) TFR(26) TFR(6)
  x0 += k0; x1 += k1 + 3u;
  TFR(17) TFR(29) TFR(16) TFR(24)
  x0 += k1; x1 += k2 + 4u;
  TFR(13) TFR(15) TFR(26) TFR(6)
  x0 += k2; x1 += k0 + 5u;
  o0 = x0; o1 = x1;
}
#undef TFR

// uniform bits -> N(0,1) exactly like jax.random.normal (XLA erfinv poly)
__device__ __forceinline__ float nrm_from_bits(uint32_t bits) {
  float f = __uint_as_float((bits >> 9) | 0x3f800000u) - 1.0f;  // [0,1)
  const float lo = -0.99999994f;                                 // nextafter(-1,0)
  float u = fmaxf(lo, __fadd_rn(__fmul_rn(f, 2.0f), lo));        // (hi-lo)==2.0f in f32
  float w = -log1pf(-__fmul_rn(u, u));
  float p;
  if (w < 5.0f) {
    float ww = w - 2.5f;
    p = 2.81022636e-08f;
    p = fmaf(p, ww, 3.43273939e-07f);
    p = fmaf(p, ww, -3.5233877e-06f);
    p = fmaf(p, ww, -4.39150654e-06f);
    p = fmaf(p, ww, 0.00021858087f);
    p = fmaf(p, ww, -0.00125372503f);
    p = fmaf(p, ww, -0.00417768164f);
    p = fmaf(p, ww, 0.246640727f);
    p = fmaf(p, ww, 1.50140941f);
  } else {
    float ww = sqrtf(w) - 3.0f;
    p = -0.000200214257f;
    p = fmaf(p, ww, 0.000100950558f);
    p = fmaf(p, ww, 0.00134934322f);
    p = fmaf(p, ww, -0.00367342844f);
    p = fmaf(p, ww, 0.00573950773f);
    p = fmaf(p, ww, -0.0076224613f);
    p = fmaf(p, ww, 0.00943887047f);
    p = fmaf(p, ww, 1.00167406f);
    p = fmaf(p, ww, 2.83297682f);
  }
  return 1.41421354f * (p * u);   // sqrt(2) * erfinv(u)
}

// ---------------- 64x64 MFMA tile (4 ntiles/wave, cond_kernel) -------------
__device__ __forceinline__ void mm_tile(const bf16_t* __restrict__ A,
                                        const bf16_t* __restrict__ Wp,
                                        f32x4 acc[16]) {
  #pragma unroll
  for (int i = 0; i < 16; ++i) acc[i] = f32x4{0.f, 0.f, 0.f, 0.f};
  #pragma unroll 2
  for (int kc = 0; kc < 8; ++kc) {
    bf16x8 a[4], b[4];
    #pragma unroll
    for (int rt = 0; rt < 4; ++rt)
      a[rt] = *(const bf16x8*)(A + rt * 16 * KP + kc * 32);
    #pragma unroll
    for (int ct = 0; ct < 4; ++ct)
      b[ct] = *(const bf16x8*)(Wp + ct * 4096 + kc * 512);
    #pragma unroll
    for (int rt = 0; rt < 4; ++rt)
      #pragma unroll
      for (int ct = 0; ct < 4; ++ct)
        acc[rt * 4 + ct] =
            __builtin_amdgcn_mfma_f32_16x16x32_bf16(a[rt], b[ct], acc[rt * 4 + ct], 0, 0, 0);
  }
}

// ---------------- 64x32 MFMA tile, bias-folded C init ----------------------
// acc[rt*2+ct] lanes = 4 rows of column (colw+ct) -> init with ini[ct].
__device__ __forceinline__ void mm_tile2(const bf16_t* __restrict__ A,
                                         const bf16_t* __restrict__ Wp,
                                         f32x4 acc[8], f32x2 ini) {
  #pragma unroll
  for (int rt = 0; rt < 4; ++rt)
    #pragma unroll
    for (int ct = 0; ct < 2; ++ct)
      acc[rt * 2 + ct] = f32x4{ini[ct], ini[ct], ini[ct], ini[ct]};
  #pragma unroll 2
  for (int kc = 0; kc < 8; ++kc) {
    bf16x8 a[4], b[2];
    #pragma unroll
    for (int rt = 0; rt < 4; ++rt)
      a[rt] = *(const bf16x8*)(A + rt * 16 * KP + kc * 32);
    #pragma unroll
    for (int ct = 0; ct < 2; ++ct)
      b[ct] = *(const bf16x8*)(Wp + ct * 4096 + kc * 512);
    #pragma unroll
    for (int rt = 0; rt < 4; ++rt)
      #pragma unroll
      for (int ct = 0; ct < 2; ++ct)
        acc[rt * 2 + ct] =
            __builtin_amdgcn_mfma_f32_16x16x32_bf16(a[rt], b[ct], acc[rt * 2 + ct], 0, 0, 0);
  }
}

// 32x32 MFMA tile for the pred GEMM (rows pre-offset in A), bias-folded
__device__ __forceinline__ void mm_tile22(const bf16_t* __restrict__ A,
                                          const bf16_t* __restrict__ Wp,
                                          f32x4 acc[4], f32x2 ini) {
  #pragma unroll
  for (int rt = 0; rt < 2; ++rt)
    #pragma unroll
    for (int ct = 0; ct < 2; ++ct)
      acc[rt * 2 + ct] = f32x4{ini[ct], ini[ct], ini[ct], ini[ct]};
  #pragma unroll 2
  for (int kc = 0; kc < 8; ++kc) {
    bf16x8 a[2], b[2];
    #pragma unroll
    for (int rt = 0; rt < 2; ++rt)
      a[rt] = *(const bf16x8*)(A + rt * 16 * KP + kc * 32);
    #pragma unroll
    for (int ct = 0; ct < 2; ++ct)
      b[ct] = *(const bf16x8*)(Wp + ct * 4096 + kc * 512);
    #pragma unroll
    for (int rt = 0; rt < 2; ++rt)
      #pragma unroll
      for (int ct = 0; ct < 2; ++ct)
        acc[rt * 2 + ct] =
            __builtin_amdgcn_mfma_f32_16x16x32_bf16(a[rt], b[ct], acc[rt * 2 + ct], 0, 0, 0);
  }
}

// Dual + K-extension: one A pass (lcond) feeds TWO B's -> skip (acc1) +
// y1 (acc2), each with per-column C init (tskip / tw1); then one extra
// K=32 block with A = lxb (x as bf16, zero-padded) and B = compact bot
// fragment tiles BS/BW (zero-padded rows 4..31).
__device__ __forceinline__ void mm_tile2_dual(const bf16_t* __restrict__ A,
                                              const bf16_t* __restrict__ W1,
                                              const bf16_t* __restrict__ W2,
                                              const bf16_t* __restrict__ lxb,
                                              const bf16_t* __restrict__ BS,
                                              const bf16_t* __restrict__ BW,
                                              int l16, int quad,
                                              f32x4 acc1[8], f32x4 acc2[8],
                                              f32x2 ini1, f32x2 ini2) {
  #pragma unroll
  for (int rt = 0; rt < 4; ++rt)
    #pragma unroll
    for (int ct = 0; ct < 2; ++ct) {
      acc1[rt * 2 + ct] = f32x4{ini1[ct], ini1[ct], ini1[ct], ini1[ct]};
      acc2[rt * 2 + ct] = f32x4{ini2[ct], ini2[ct], ini2[ct], ini2[ct]};
    }
  #pragma unroll 2
  for (int kc = 0; kc < 8; ++kc) {
    bf16x8 a[4];
    #pragma unroll
    for (int rt = 0; rt < 4; ++rt)
      a[rt] = *(const bf16x8*)(A + rt * 16 * KP + kc * 32);
    #pragma unroll
    for (int ct = 0; ct < 2; ++ct) {
      bf16x8 b = *(const bf16x8*)(W1 + ct * 4096 + kc * 512);
      #pragma unroll
      for (int rt = 0; rt < 4; ++rt)
        acc1[rt * 2 + ct] =
            __builtin_amdgcn_mfma_f32_16x16x32_bf16(a[rt], b, acc1[rt * 2 + ct], 0, 0, 0);
    }
    #pragma unroll
    for (int ct = 0; ct < 2; ++ct) {
      bf16x8 b = *(const bf16x8*)(W2 + ct * 4096 + kc * 512);
      #pragma unroll
      for (int rt = 0; rt < 4; ++rt)
        acc2[rt * 2 + ct] =
            __builtin_amdgcn_mfma_f32_16x16x32_bf16(a[rt], b, acc2[rt * 2 + ct], 0, 0, 0);
    }
  }
  // extra K=32 block: x @ bot (rank-4 update on the matrix pipe)
  {
    bf16x8 ax[4];
    #pragma unroll
    for (int rt = 0; rt < 4; ++rt)
      ax[rt] = *(const bf16x8*)(lxb + (rt * 16 + l16) * 32 + quad * 8);
    #pragma unroll
    for (int ct = 0; ct < 2; ++ct) {
      bf16x8 b = *(const bf16x8*)(BS + ct * 512);
      #pragma unroll
      for (int rt = 0; rt < 4; ++rt)
        acc1[rt * 2 + ct] =
            __builtin_amdgcn_mfma_f32_16x16x32_bf16(ax[rt], b, acc1[rt * 2 + ct], 0, 0, 0);
    }
    #pragma unroll
    for (int ct = 0; ct < 2; ++ct) {
      bf16x8 b = *(const bf16x8*)(BW + ct * 512);
      #pragma unroll
      for (int rt = 0; rt < 4; ++rt)
        acc2[rt * 2 + ct] =
            __builtin_amdgcn_mfma_f32_16x16x32_bf16(ax[rt], b, acc2[rt * 2 + ct], 0, 0, 0);
    }
  }
}

// ---------------- kernel 1: weight repack ----------------------------------
// Tiles 0..9 full: e=[m][nt][kc][lane][j], value src_m[k*256+n],
//   n = (nt>>1)*32 + (lane&15)*2 + (nt&1), k = kc*32 + (lane>>4)*8 + j.
// Tile 10 (fw, compact nt 0..1): final_w 256x4 zero-padded.
// Tiles 11/12 (bot frags, 16 nt x 1 kc): rows 0..3 = bot rows (512..515 of
//   blk0_skip_w / blk0_w1), rows 4..31 zero.
__global__ void wprep_kernel(const float* __restrict__ condw,
                             const float* __restrict__ w1,
                             const float* __restrict__ skw,
                             const float* __restrict__ w2,
                             const float* __restrict__ bw1,
                             const float* __restrict__ bw2,
                             const float* __restrict__ fw,
                             bf16_t* __restrict__ wts) {
  int e = blockIdx.x * 256 + threadIdx.x;
  if (e >= WT_TOT) return;
  if (e >= WT_BS) {                            // compact bot fragment tiles
    int r2 = e - WT_BS;
    int which = r2 >> 13;                      // 0 = skipbot, 1 = w1bot
    int rr = r2 & 8191;
    int nt2 = rr >> 9, lane2 = (rr >> 3) & 63, j2 = rr & 7;
    int n2 = (nt2 >> 1) * 32 + (lane2 & 15) * 2 + (nt2 & 1);
    int kr = (lane2 >> 4) * 8 + j2;            // 0..31
    const float* src2 = which ? w1 : skw;      // bot rows = rows 512+kr
    wts[e] = (kr < 4) ? (bf16_t)src2[(512 + kr) * 256 + n2] : (bf16_t)0.f;
    return;
  }
  int m = e >> 16;
  int r = e & 65535;
  int nt = r >> 12, kc = (r >> 9) & 7, lane = (r >> 3) & 63, j = r & 7;
  int n = (nt >> 1) * 32 + (lane & 15) * 2 + (nt & 1);
  int k = kc * 32 + (lane >> 4) * 8 + j;
  if (m == 10) {                               // compact final_w tile
    wts[e] = (n < 4) ? (bf16_t)fw[k * 4 + n] : (bf16_t)0.f;
    return;
  }
  const float* src;
  if      (m == 0) src = condw;
  else if (m == 1) src = w1;                    // blk0_w1 rows 0..255 (cond part)
  else if (m == 2) src = skw;                   // blk0_skip_w rows 0..255
  else if (m == 3) src = w2;                    // blk0_w2
  else if (m <= 6) src = bw1 + (m - 4) * 65536; // blks_w1[i]
  else             src = bw2 + (m - 7) * 65536; // blks_w2[i]
  wts[e] = (bf16_t)src[k * 256 + n];
}

// ---------------- kernel 2: per-step vectors + scalars ---------------------
__global__ void prep_kernel(const float* __restrict__ time_w,
                            const float* __restrict__ time_b,
                            const float* __restrict__ w1,
                            const float* __restrict__ b1,
                            const float* __restrict__ skw,
                            const float* __restrict__ skb,
                            float* __restrict__ tvecs,
                            float* __restrict__ stepsc) {
  int s = blockIdx.x;          // 0..9, t = 90 - 10*s
  int j = threadIdx.x;         // 0..255
  int t = 90 - s * 10;
  float tval = (float)t;
  __shared__ float emb[256];
  __shared__ float temb[256];
  if (j < 128) {
    float freq = expf((float)j * -0.07252236513366287f);  // -ln(1e4)/127
    float e = tval * freq;
    emb[j] = sinf(e);
    emb[j + 128] = cosf(e);
  }
  __syncthreads();
  float a = time_b[j];
  for (int k = 0; k < 256; ++k) a = fmaf(emb[k], time_w[k * 256 + j], a);
  temb[j] = gelu_f(a);
  __syncthreads();
  float v1 = b1[j], v2 = skb[j];
  for (int k = 0; k < 256; ++k) {
    float tk = temb[k];
    v1 = fmaf(tk, w1[(256 + k) * 256 + j], v1);    // blk0_w1 rows 256..511
    v2 = fmaf(tk, skw[(256 + k) * 256 + j], v2);   // blk0_skip_w rows 256..511
  }
  tvecs[s * 512 + j] = v1;         // tw1 (includes b1)
  tvecs[s * 512 + 256 + j] = v2;   // tskip (includes skip_b)
  if (j == 0) {
    float step = (0.02f - 1e-4f) / 99.0f;
    float acp = 1.0f, beta = 0.0f;
    for (int i = 0; i <= t; ++i) {
      beta = fmaf((float)i, step, 1e-4f);
      acp *= (1.0f - beta);
    }
    stepsc[s * 4 + 0] = 1.0f / sqrtf(1.0f - beta);   // 1/sqrt(alpha)
    stepsc[s * 4 + 1] = beta / sqrtf(1.0f - acp);    // b/sqrt(1-acp)
    stepsc[s * 4 + 2] = (t > 0) ? sqrtf(beta) : 0.0f;
    stepsc[s * 4 + 3] = 0.0f;
  }
}

// ---------------- kernel 3: x0 + noises via PARTITIONABLE threefry ---------
__global__ void noise_kernel(float* __restrict__ xout, float* __restrict__ nout, int nb) {
  int gid = blockIdx.x * 256 + threadIdx.x;
  int nx = nb * 4;     // 131072 x0 elements
  int nn = nb * 40;    // 1310720 noise elements
  uint32_t k0, k1, o0, o1;
  if (gid < nx) {
    tf2(0u, 42u, 0u, 999u, k0, k1);                 // fold_in(key(42), 999)
    tf2(k0, k1, 0u, (uint32_t)gid, o0, o1);
    xout[gid] = nrm_from_bits(o0 ^ o1);
  } else if (gid < nx + nn) {
    int i = gid - nx;
    tf2(0u, 42u, 0u, 7u, k0, k1);                   // fold_in(key(42), 7)
    tf2(k0, k1, 0u, (uint32_t)i, o0, o1);
    nout[i] = nrm_from_bits(o0 ^ o1);
  }
}

// ---------------- kernel 4: cond = features @ cond_w + cond_b --------------
__global__ __launch_bounds__(256, 2) void cond_kernel(
    const float* __restrict__ feat, const bf16_t* __restrict__ wts,
    const float* __restrict__ condb, bf16_t* __restrict__ condg) {
  __shared__ __align__(16) bf16_t la[MTILE * KP];
  const int tid = threadIdx.x;
  const int wave = tid >> 6, lane = tid & 63, quad = lane >> 4, l16 = lane & 15;
  const int rowbase = blockIdx.x * MTILE;
  for (int it = 0; it < 16; ++it) {
    int e = (it * 256 + tid) * 4;
    int rr = e >> 8, c = e & 255;
    f32x4 v = *(const f32x4*)(feat + (size_t)(rowbase + rr) * 256 + c);
    bf16x4 bv;
    bv[0] = (bf16_t)v[0]; bv[1] = (bf16_t)v[1];
    bv[2] = (bf16_t)v[2]; bv[3] = (bf16_t)v[3];
    *(bf16x4*)(la + rr * KP + c) = bv;
  }
  __syncthreads();
  f32x4 acc[16];
  mm_tile(la + l16 * KP + quad * 8, wts + wave * 16384 + lane * 8, acc);
  const int c0 = wave * 64 + l16 * 2;            // ct 0,1 -> c0, ct 2,3 -> c0+32
  f32x2 b0 = *(const f32x2*)(condb + c0);
  f32x2 b1 = *(const f32x2*)(condb + c0 + 32);
  #pragma unroll
  for (int rt = 0; rt < 4; ++rt)
    #pragma unroll
    for (int r = 0; r < 4; ++r) {
      int row = rt * 16 + quad * 4 + r;
      bf16x2 p0, p1;
      p0[0] = (bf16_t)(acc[rt * 4 + 0][r] + b0[0]);
      p0[1] = (bf16_t)(acc[rt * 4 + 1][r] + b0[1]);
      p1[0] = (bf16_t)(acc[rt * 4 + 2][r] + b1[0]);
      p1[1] = (bf16_t)(acc[rt * 4 + 3][r] + b1[1]);
      *(bf16x2*)(condg + (size_t)(rowbase + row) * 256 + c0) = p0;
      *(bf16x2*)(condg + (size_t)(rowbase + row) * 256 + c0 + 32) = p1;
    }
}

// ---------------- kernel 5: fused 10-step sampler (512 thr / 8 waves) ------
// r17 champion structure + x@bot folded into the dual's K-dim.
__global__ __launch_bounds__(512, 1) void fused_kernel(
    const bf16_t* __restrict__ condg, const bf16_t* __restrict__ wts,
    const float* __restrict__ tvecs, const float* __restrict__ stepsc,
    const float* __restrict__ x0w, const float* __restrict__ noises,
    const float* __restrict__ b2v, const float* __restrict__ blksb1,
    const float* __restrict__ blksb2,
    const float* __restrict__ finalb, float* __restrict__ out, int nb) {
  __shared__ __align__(16) bf16_t lcond[MTILE * KP];
  __shared__ __align__(16) bf16_t lact0[MTILE * KP];   // double-buffered act
  __shared__ __align__(16) bf16_t lact1[MTILE * KP];
  __shared__ __align__(16) float  lx[MTILE * 4];
  __shared__ __align__(16) bf16_t lxb[MTILE * 32];     // x as bf16, K-extension A
  const int tid = threadIdx.x;
  const int wave = tid >> 6, lane = tid & 63, quad = lane >> 4, l16 = lane & 15;
  const int rowbase = blockIdx.x * MTILE;

  // stage cond tile (persists all 10 steps) + x0 (+ lxb init)
  {
    int rr = tid >> 3, c = (tid & 7) * 32;
    const bf16_t* src = condg + (size_t)(rowbase + rr) * 256 + c;
    bf16_t* dst = lcond + rr * KP + c;
    #pragma unroll
    for (int j = 0; j < 4; ++j)
      *(bf16x8*)(dst + j * 8) = *(const bf16x8*)(src + j * 8);
  }
  for (int i = tid; i < MTILE * 32; i += 512)
    if ((i & 31) >= 4) lxb[i] = (bf16_t)0.f;   // zero pad cols 4..31 (once)
  if (tid < 256) {
    float xv = x0w[rowbase * 4 + tid];
    lx[tid] = xv;
    lxb[(tid >> 2) * 32 + (tid & 3)] = (bf16_t)xv;
  }
  __syncthreads();

  const bf16_t* Acond = lcond + l16 * KP + quad * 8;
  const bf16_t* A0    = lact0 + l16 * KP + quad * 8;
  const bf16_t* A1    = lact1 + l16 * KP + quad * 8;
  const int colw = wave * 32 + l16 * 2;          // 2 consecutive cols/lane
  const int wlane = wave * 8192 + lane * 8;
  const bf16_t* BS = wts + WT_BS + wave * 1024 + lane * 8;  // skipbot frag
  const bf16_t* BW = wts + WT_BW + wave * 1024 + lane * 8;  // w1bot frag
  f32x4 resid[8], work[8];

  // step-invariant per-column constants, hoisted to registers
  const f32x2 b2c = *(const f32x2*)(b2v + colw);
  f32x2 g1c[3], g2c[3];
  #pragma unroll
  for (int blk = 0; blk < 3; ++blk) {
    g1c[blk] = *(const f32x2*)(blksb1 + blk * 256 + colw);
    g2c[blk] = *(const f32x2*)(blksb2 + blk * 256 + colw);
  }
  f32x2 fbc;
  {
    int bi = (l16 < 2) ? (int)(l16 * 2) : 0;   // valid lanes only; rest unused
    fbc[0] = finalb[bi]; fbc[1] = finalb[bi + 1];
  }

  // pack lane's 2 consecutive cols -> one ds_write_b32 per (rt,r)
  auto write_act = [&](bf16_t* dst) {
    #pragma unroll
    for (int rt = 0; rt < 4; ++rt)
      #pragma unroll
      for (int r = 0; r < 4; ++r) {
        bf16x2 pv;
        pv[0] = (bf16_t)work[rt * 2 + 0][r];
        pv[1] = (bf16_t)work[rt * 2 + 1][r];
        *(bf16x2*)(dst + (rt * 16 + quad * 4 + r) * KP + colw) = pv;
      }
  };
  auto epi_gelu = [&]() {        // bias already in acc init
    #pragma unroll
    for (int rt = 0; rt < 4; ++rt)
      #pragma unroll
      for (int r = 0; r < 4; ++r) {
        f32x2 v = gelu2(f32x2{work[rt * 2][r], work[rt * 2 + 1][r]});
        work[rt * 2][r] = v[0]; work[rt * 2 + 1][r] = v[1];
      }
  };
  auto epi_gelu_res = [&]() {    // bias already in acc init
    #pragma unroll
    for (int rt = 0; rt < 4; ++rt)
      #pragma unroll
      for (int r = 0; r < 4; ++r) {
        f32x2 v = gelu2(f32x2{work[rt * 2][r], work[rt * 2 + 1][r]})
                + f32x2{resid[rt * 2][r], resid[rt * 2 + 1][r]};
        resid[rt * 2][r] = v[0]; resid[rt * 2 + 1][r] = v[1];
        work[rt * 2][r] = v[0];  work[rt * 2 + 1][r] = v[1];
      }
  };

  for (int s = 0; s < 10; ++s) {
    const float* tw  = tvecs + s * 512;
    const float* tsk = tvecs + s * 512 + 256;
    f32x2 tcw = *(const f32x2*)(tw + colw);
    f32x2 tcs = *(const f32x2*)(tsk + colw);
    // skip -> resid (C init = tskip), y1 -> work (C init = tw1):
    // ONE lcond pass + K-extension (x@bot). resid is COMPLETE from MFMA;
    // work only needs gelu.
    mm_tile2_dual(Acond, wts + 2 * 65536 + wlane, wts + 1 * 65536 + wlane,
                  lxb, BS, BW, l16, quad, resid, work, tcs, tcw);
    epi_gelu();
    write_act(lact0);
    __syncthreads();                               // B1: y1 in lact0
    // h = gelu(y1 @ W2 + b2) + skip                -> lact1
    mm_tile2(A0, wts + 3 * 65536 + wlane, work, b2c);
    epi_gelu_res();
    write_act(lact1);     // != read buffer: no pre-barrier needed
    __syncthreads();                               // B2: h in lact1
    // 3 residual blocks: g1 lact1->lact0, g2 lact0->lact1
    for (int blk = 0; blk < 3; ++blk) {
      mm_tile2(A1, wts + (4 + blk) * 65536 + wlane, work, g1c[blk]);
      epi_gelu();
      write_act(lact0);
      __syncthreads();                             // g1 in lact0
      mm_tile2(A0, wts + (7 + blk) * 65536 + wlane, work, g2c[blk]);
      epi_gelu_res();
      write_act(lact1);
      __syncthreads();                             // g2 in lact1
    }
    // pred = h @ final_w + final_b via MFMA (waves 0,1: 32 rows each)
    if (wave < 2) {
      f32x4 pacc[4];
      mm_tile22(lact1 + (wave * 32 + l16) * KP + quad * 8,
                wts + WT_FW + lane * 8, pacc, fbc);  // + final_b folded
      if (l16 < 2) {
        f32x4 sc = *(const f32x4*)(stepsc + s * 4);
        #pragma unroll
        for (int ct = 0; ct < 2; ++ct) {
          int col = l16 * 2 + ct;
          #pragma unroll
          for (int rt = 0; rt < 2; ++rt)
            #pragma unroll
            for (int r = 0; r < 4; ++r) {
              int row = wave * 32 + rt * 16 + quad * 4 + r;
              float accp = pacc[rt * 2 + ct][r];
              float xv = lx[row * 4 + col];
              xv = (xv - sc[1] * accp) * sc[0];
              xv = fmaf(sc[2],
                        noises[(size_t)s * nb * 4 + (size_t)(rowbase + row) * 4 + col],
                        xv);
              lx[row * 4 + col] = xv;            // readers only after B9
              lxb[row * 32 + col] = (bf16_t)xv;  // K-extension A for next step
            }
        }
      }
    }
    __syncthreads();                               // B9: lx/lxb visible
  }
  if (tid < 256) {
    float xf = lx[tid];
    xf = fminf(1.0f, fmaxf(-1.0f, xf));
    out[rowbase * 4 + tid] = xf;
  }
}

// ---------------------------------------------------------------------------
extern "C" void kernel_launch(void* const* d_in, const int* in_sizes, int n_in,
                              void* d_out, int out_size, void* d_ws, size_t ws_size,
                              hipStream_t stream) {
  (void)n_in; (void)out_size; (void)ws_size;
  const float* features    = (const float*)d_in[0];
  const float* cond_w      = (const float*)d_in[1];
  const float* cond_b      = (const float*)d_in[2];
  const float* time_w      = (const float*)d_in[3];
  const float* time_b      = (const float*)d_in[4];
  const float* blk0_w1     = (const float*)d_in[5];
  const float* blk0_b1     = (const float*)d_in[6];
  const float* blk0_w2     = (const float*)d_in[7];
  const float* blk0_b2     = (const float*)d_in[8];
  const float* blk0_skip_w = (const float*)d_in[9];
  const float* blk0_skip_b = (const float*)d_in[10];
  const float* blks_w1     = (const float*)d_in[11];
  const float* blks_b1     = (const float*)d_in[12];
  const float* blks_w2     = (const float*)d_in[13];
  const float* blks_b2     = (const float*)d_in[14];
  const float* final_w     = (const float*)d_in[15];
  const float* final_b     = (const float*)d_in[16];

  const int nb = in_sizes[0] / 256;   // batch (32768)

  // workspace layout (bytes, 256-aligned)
  char* ws = (char*)d_ws;
  bf16_t* wts    = (bf16_t*)(ws + 0);        // 679936 bf16 = 1,359,872 B
  float*  tvecs  = (float*)(ws + 1359872);   // 10 * 512 f32    = 20,480 B
  float*  stepsc = (float*)(ws + 1380352);   // 10 * 4 f32      (pad to 256)
  float*  x0w    = (float*)(ws + 1380608);   // nb*4 f32        = 524,288 B
  float*  noisew = (float*)(ws + 1904896);   // 10*nb*4 f32     = 5,242,880 B
  bf16_t* condw  = (bf16_t*)(ws + 7147776);  // nb*256 bf16     = 16,777,216 B

  wprep_kernel<<<(WT_TOT + 255) / 256, 256, 0, stream>>>(
      cond_w, blk0_w1, blk0_skip_w, blk0_w2, blks_w1, blks_w2, final_w, wts);
  prep_kernel<<<10, 256, 0, stream>>>(time_w, time_b, blk0_w1, blk0_b1,
                                      blk0_skip_w, blk0_skip_b, tvecs, stepsc);
  noise_kernel<<<(nb * 44 + 255) / 256, 256, 0, stream>>>(x0w, noisew, nb);
  cond_kernel<<<nb / MTILE, 256, 0, stream>>>(features, wts, cond_b, condw);
  fused_kernel<<<nb / MTILE, 512, 0, stream>>>(
      condw, wts, tvecs, stepsc, x0w, noisew,
      blk0_b2, blks_b1, blks_b2, final_b, (float*)d_out, nb);
}

// Round 19
// 628.550 us; speedup vs baseline: 1.5533x; 1.0006x over previous
//
#include <hip/hip_runtime.h>
#include <stdint.h>
#include <stddef.h>

// ---------------------------------------------------------------------------
// DiffusionActionHead: fully fused 10-step DDPM sampler, bf16 MFMA.
//   B=32768, H=256, A=4, 10 inference steps.
//   1. wprep_kernel  : repack 10 weight matrices + fw tile + 2 compact bot
//                      fragment tiles (x@bot fold) -> bf16 MFMA-B frags
//   2. prep_kernel   : per-step temb-derived col-vectors tw1/tskip + scalars
//   3. noise_kernel  : JAX threefry2x32, PARTITIONABLE counter scheme
//   4. cond_kernel   : cond = features @ cond_w + cond_b  (bf16 out)
//   5. fused_kernel  : 10 steps x 9 K-extended GEMMs per 64-row tile.
//      ROUND 19 (r18 = champion 580us fused; remaining serialization:
//      waves 2-7 idle at the step-end barrier while waves 0,1 run pred):
//        - SOFTWARE-PIPELINE pred: defer pred_{s-1} into step s. Per step:
//          (1) ALL waves issue dual-main (lcond @ W1/W2, x-INDEPENDENT)
//          into registers; (2) waves 0,1 concurrently run pred_{s-1} +
//          x-update -> lx/lxb; (3) barrier P; (4) all waves run the
//          K-extension (lxb @ bot) + gelu + write. Pred tail leaves the
//          critical path (waves 0,1 co-issue with waves 4,5 per SIMD).
//        - dep-audit: pred_{s-1} reads lact1=h_{s-1}, next written 2
//          barriers later (W2 phase) OK; lxb write->read split by P OK;
//          s=0 skips pred (x0 preloaded); epilogue runs pred_9.
//        - regs: resid+work(64 acc) + pacc(16) + ~100 arch ~= 180 <= 256.
//        - everything else = r18: MTILE=64, dual GEMM + x@bot K-fold,
//          dbuf lact (9 barriers), bias-folded C init, tanh-gelu, KP=272.
// ---------------------------------------------------------------------------

typedef __bf16 bf16_t;
typedef __bf16 bf16x8 __attribute__((ext_vector_type(8)));
typedef __bf16 bf16x4 __attribute__((ext_vector_type(4)));
typedef __bf16 bf16x2 __attribute__((ext_vector_type(2)));
typedef float  f32x4  __attribute__((ext_vector_type(4)));
typedef float  f32x2  __attribute__((ext_vector_type(2)));

constexpr int KP    = 272;   // LDS row stride in bf16 elems (256 + 16 pad)
constexpr int MTILE = 64;    // rows per workgroup

// wts layout (bf16 elems): tiles 0..9 full (65536 each), tile10 fw (8192),
// tile11 skipbot-frag (8192), tile12 w1bot-frag (8192). total 679936.
constexpr int WT_FW  = 10 * 65536;            // 655360
constexpr int WT_BS  = WT_FW + 8192;          // 663552 (skipbot frag)
constexpr int WT_BW  = WT_BS + 8192;          // 671744 (w1bot frag)
constexpr int WT_TOT = WT_BW + 8192;          // 679936

// ---------------- packed f32x2 helpers -------------------------------------
__device__ __forceinline__ f32x2 bc2(float v) { return f32x2{v, v}; }
__device__ __forceinline__ f32x2 fma2(f32x2 a, f32x2 b, f32x2 c) {
#if __has_builtin(__builtin_elementwise_fma)
  return __builtin_elementwise_fma(a, b, c);
#else
  return f32x2{fmaf(a[0], b[0], c[0]), fmaf(a[1], b[1], c[1])};
#endif
}

// ---------------- exact-erf GELU (A&S 7.1.26) for prep_kernel ---------------
__device__ __forceinline__ float gelu_f(float x) {
  float z  = 0.70710678f * x;
  float az = fabsf(z);
  float t  = __builtin_amdgcn_rcpf(fmaf(0.3275911f, az, 1.0f));
  float e  = __expf(-az * az);
  float p  = fmaf(1.061405429f, t, -1.453152027f);
  p = fmaf(p, t, 1.421413741f);
  p = fmaf(p, t, -0.284496736f);
  p = fmaf(p, t, 0.254829592f);
  float er = fmaf(-(p * t), e, 1.0f);   // erf(|z|)
  er = copysignf(er, z);
  return 0.5f * x * (1.0f + er);
}
// packed tanh-form GELU via sigmoid identity (r17-verified):
//   gelu(x) = x - x / (exp2(m) + 1),  m = x*(A + B*x^2)
//   A = 2*0.7978845608*log2(e) = 2.30211784, B = A*0.044715 = 0.10293942
__device__ __forceinline__ f32x2 gelu2(f32x2 x) {
  f32x2 x2 = x * x;
  f32x2 p  = fma2(bc2(0.10293942f), x2, bc2(2.30211784f));
  f32x2 m  = x * p;
  f32x2 e;
  e[0] = __builtin_amdgcn_exp2f(m[0]);
  e[1] = __builtin_amdgcn_exp2f(m[1]);
  f32x2 d  = e + bc2(1.0f);
  f32x2 r;
  r[0] = __builtin_amdgcn_rcpf(d[0]);
  r[1] = __builtin_amdgcn_rcpf(d[1]);
  return fma2(-x, r, x);     // x * sigmoid(2u)
}

// ---------------- JAX threefry2x32 (20 rounds) ------------------------------
#define TFR(a) x0 += x1; x1 = (x1 << (a)) | (x1 >> (32 - (a))); x1 ^= x0;
__device__ __forceinline__ void tf2(uint32_t k0, uint32_t k1,
                                    uint32_t x0, uint32_t x1,
                                    uint32_t& o0, uint32_t& o1) {
  uint32_t k2 = k0 ^ k1 ^ 0x1BD11BDAu;
  x0 += k0; x1 += k1;
  TFR(13) TFR(15) TFR(26) TFR(6)
  x0 += k1; x1 += k2 + 1u;
  TFR(17) TFR(29) TFR(16) TFR(24)
  x0 += k2; x1 += k0 + 2u;
  TFR(13) TFR(15) TFR(26) TFR(6)
  x0 += k0; x1 += k1 + 3u;
  TFR(17) TFR(29) TFR(16) TFR(24)
  x0 += k1; x1 += k2 + 4u;
  TFR(13) TFR(15) TFR(26) TFR(6)
  x0 += k2; x1 += k0 + 5u;
  o0 = x0; o1 = x1;
}
#undef TFR

// uniform bits -> N(0,1) exactly like jax.random.normal (XLA erfinv poly)
__device__ __forceinline__ float nrm_from_bits(uint32_t bits) {
  float f = __uint_as_float((bits >> 9) | 0x3f800000u) - 1.0f;  // [0,1)
  const float lo = -0.99999994f;                                 // nextafter(-1,0)
  float u = fmaxf(lo, __fadd_rn(__fmul_rn(f, 2.0f), lo));        // (hi-lo)==2.0f in f32
  float w = -log1pf(-__fmul_rn(u, u));
  float p;
  if (w < 5.0f) {
    float ww = w - 2.5f;
    p = 2.81022636e-08f;
    p = fmaf(p, ww, 3.43273939e-07f);
    p = fmaf(p, ww, -3.5233877e-06f);
    p = fmaf(p, ww, -4.39150654e-06f);
    p = fmaf(p, ww, 0.00021858087f);
    p = fmaf(p, ww, -0.00125372503f);
    p = fmaf(p, ww, -0.00417768164f);
    p = fmaf(p, ww, 0.246640727f);
    p = fmaf(p, ww, 1.50140941f);
  } else {
    float ww = sqrtf(w) - 3.0f;
    p = -0.000200214257f;
    p = fmaf(p, ww, 0.000100950558f);
    p = fmaf(p, ww, 0.00134934322f);
    p = fmaf(p, ww, -0.00367342844f);
    p = fmaf(p, ww, 0.00573950773f);
    p = fmaf(p, ww, -0.0076224613f);
    p = fmaf(p, ww, 0.00943887047f);
    p = fmaf(p, ww, 1.00167406f);
    p = fmaf(p, ww, 2.83297682f);
  }
  return 1.41421354f * (p * u);   // sqrt(2) * erfinv(u)
}

// ---------------- 64x64 MFMA tile (4 ntiles/wave, cond_kernel) -------------
__device__ __forceinline__ void mm_tile(const bf16_t* __restrict__ A,
                                        const bf16_t* __restrict__ Wp,
                                        f32x4 acc[16]) {
  #pragma unroll
  for (int i = 0; i < 16; ++i) acc[i] = f32x4{0.f, 0.f, 0.f, 0.f};
  #pragma unroll 2
  for (int kc = 0; kc < 8; ++kc) {
    bf16x8 a[4], b[4];
    #pragma unroll
    for (int rt = 0; rt < 4; ++rt)
      a[rt] = *(const bf16x8*)(A + rt * 16 * KP + kc * 32);
    #pragma unroll
    for (int ct = 0; ct < 4; ++ct)
      b[ct] = *(const bf16x8*)(Wp + ct * 4096 + kc * 512);
    #pragma unroll
    for (int rt = 0; rt < 4; ++rt)
      #pragma unroll
      for (int ct = 0; ct < 4; ++ct)
        acc[rt * 4 + ct] =
            __builtin_amdgcn_mfma_f32_16x16x32_bf16(a[rt], b[ct], acc[rt * 4 + ct], 0, 0, 0);
  }
}

// ---------------- 64x32 MFMA tile, bias-folded C init ----------------------
// acc[rt*2+ct] lanes = 4 rows of column (colw+ct) -> init with ini[ct].
__device__ __forceinline__ void mm_tile2(const bf16_t* __restrict__ A,
                                         const bf16_t* __restrict__ Wp,
                                         f32x4 acc[8], f32x2 ini) {
  #pragma unroll
  for (int rt = 0; rt < 4; ++rt)
    #pragma unroll
    for (int ct = 0; ct < 2; ++ct)
      acc[rt * 2 + ct] = f32x4{ini[ct], ini[ct], ini[ct], ini[ct]};
  #pragma unroll 2
  for (int kc = 0; kc < 8; ++kc) {
    bf16x8 a[4], b[2];
    #pragma unroll
    for (int rt = 0; rt < 4; ++rt)
      a[rt] = *(const bf16x8*)(A + rt * 16 * KP + kc * 32);
    #pragma unroll
    for (int ct = 0; ct < 2; ++ct)
      b[ct] = *(const bf16x8*)(Wp + ct * 4096 + kc * 512);
    #pragma unroll
    for (int rt = 0; rt < 4; ++rt)
      #pragma unroll
      for (int ct = 0; ct < 2; ++ct)
        acc[rt * 2 + ct] =
            __builtin_amdgcn_mfma_f32_16x16x32_bf16(a[rt], b[ct], acc[rt * 2 + ct], 0, 0, 0);
  }
}

// 32x32 MFMA tile for the pred GEMM (rows pre-offset in A), bias-folded
__device__ __forceinline__ void mm_tile22(const bf16_t* __restrict__ A,
                                          const bf16_t* __restrict__ Wp,
                                          f32x4 acc[4], f32x2 ini) {
  #pragma unroll
  for (int rt = 0; rt < 2; ++rt)
    #pragma unroll
    for (int ct = 0; ct < 2; ++ct)
      acc[rt * 2 + ct] = f32x4{ini[ct], ini[ct], ini[ct], ini[ct]};
  #pragma unroll 2
  for (int kc = 0; kc < 8; ++kc) {
    bf16x8 a[2], b[2];
    #pragma unroll
    for (int rt = 0; rt < 2; ++rt)
      a[rt] = *(const bf16x8*)(A + rt * 16 * KP + kc * 32);
    #pragma unroll
    for (int ct = 0; ct < 2; ++ct)
      b[ct] = *(const bf16x8*)(Wp + ct * 4096 + kc * 512);
    #pragma unroll
    for (int rt = 0; rt < 2; ++rt)
      #pragma unroll
      for (int ct = 0; ct < 2; ++ct)
        acc[rt * 2 + ct] =
            __builtin_amdgcn_mfma_f32_16x16x32_bf16(a[rt], b[ct], acc[rt * 2 + ct], 0, 0, 0);
  }
}

// Dual main: one A pass (lcond) feeds TWO B's -> skip (acc1) + y1 (acc2),
// each with per-column C init (tskip / tw1). x-INDEPENDENT part only.
__device__ __forceinline__ void mm_dual_main(const bf16_t* __restrict__ A,
                                             const bf16_t* __restrict__ W1,
                                             const bf16_t* __restrict__ W2,
                                             f32x4 acc1[8], f32x4 acc2[8],
                                             f32x2 ini1, f32x2 ini2) {
  #pragma unroll
  for (int rt = 0; rt < 4; ++rt)
    #pragma unroll
    for (int ct = 0; ct < 2; ++ct) {
      acc1[rt * 2 + ct] = f32x4{ini1[ct], ini1[ct], ini1[ct], ini1[ct]};
      acc2[rt * 2 + ct] = f32x4{ini2[ct], ini2[ct], ini2[ct], ini2[ct]};
    }
  #pragma unroll 2
  for (int kc = 0; kc < 8; ++kc) {
    bf16x8 a[4];
    #pragma unroll
    for (int rt = 0; rt < 4; ++rt)
      a[rt] = *(const bf16x8*)(A + rt * 16 * KP + kc * 32);
    #pragma unroll
    for (int ct = 0; ct < 2; ++ct) {
      bf16x8 b = *(const bf16x8*)(W1 + ct * 4096 + kc * 512);
      #pragma unroll
      for (int rt = 0; rt < 4; ++rt)
        acc1[rt * 2 + ct] =
            __builtin_amdgcn_mfma_f32_16x16x32_bf16(a[rt], b, acc1[rt * 2 + ct], 0, 0, 0);
    }
    #pragma unroll
    for (int ct = 0; ct < 2; ++ct) {
      bf16x8 b = *(const bf16x8*)(W2 + ct * 4096 + kc * 512);
      #pragma unroll
      for (int rt = 0; rt < 4; ++rt)
        acc2[rt * 2 + ct] =
            __builtin_amdgcn_mfma_f32_16x16x32_bf16(a[rt], b, acc2[rt * 2 + ct], 0, 0, 0);
    }
  }
}

// Dual K-extension: A = lxb (x as bf16, zero-padded), B = compact bot
// fragment tiles BS/BW (zero-padded rows 4..31). Accumulates in place.
__device__ __forceinline__ void mm_dual_ext(const bf16_t* __restrict__ lxb,
                                            const bf16_t* __restrict__ BS,
                                            const bf16_t* __restrict__ BW,
                                            int l16, int quad,
                                            f32x4 acc1[8], f32x4 acc2[8]) {
  bf16x8 ax[4];
  #pragma unroll
  for (int rt = 0; rt < 4; ++rt)
    ax[rt] = *(const bf16x8*)(lxb + (rt * 16 + l16) * 32 + quad * 8);
  #pragma unroll
  for (int ct = 0; ct < 2; ++ct) {
    bf16x8 b = *(const bf16x8*)(BS + ct * 512);
    #pragma unroll
    for (int rt = 0; rt < 4; ++rt)
      acc1[rt * 2 + ct] =
          __builtin_amdgcn_mfma_f32_16x16x32_bf16(ax[rt], b, acc1[rt * 2 + ct], 0, 0, 0);
  }
  #pragma unroll
  for (int ct = 0; ct < 2; ++ct) {
    bf16x8 b = *(const bf16x8*)(BW + ct * 512);
    #pragma unroll
    for (int rt = 0; rt < 4; ++rt)
      acc2[rt * 2 + ct] =
          __builtin_amdgcn_mfma_f32_16x16x32_bf16(ax[rt], b, acc2[rt * 2 + ct], 0, 0, 0);
  }
}

// ---------------- kernel 1: weight repack ----------------------------------
// Tiles 0..9 full: e=[m][nt][kc][lane][j], value src_m[k*256+n],
//   n = (nt>>1)*32 + (lane&15)*2 + (nt&1), k = kc*32 + (lane>>4)*8 + j.
// Tile 10 (fw, compact nt 0..1): final_w 256x4 zero-padded.
// Tiles 11/12 (bot frags, 16 nt x 1 kc): rows 0..3 = bot rows (512..515 of
//   blk0_skip_w / blk0_w1), rows 4..31 zero.
__global__ void wprep_kernel(const float* __restrict__ condw,
                             const float* __restrict__ w1,
                             const float* __restrict__ skw,
                             const float* __restrict__ w2,
                             const float* __restrict__ bw1,
                             const float* __restrict__ bw2,
                             const float* __restrict__ fw,
                             bf16_t* __restrict__ wts) {
  int e = blockIdx.x * 256 + threadIdx.x;
  if (e >= WT_TOT) return;
  if (e >= WT_BS) {                            // compact bot fragment tiles
    int r2 = e - WT_BS;
    int which = r2 >> 13;                      // 0 = skipbot, 1 = w1bot
    int rr = r2 & 8191;
    int nt2 = rr >> 9, lane2 = (rr >> 3) & 63, j2 = rr & 7;
    int n2 = (nt2 >> 1) * 32 + (lane2 & 15) * 2 + (nt2 & 1);
    int kr = (lane2 >> 4) * 8 + j2;            // 0..31
    const float* src2 = which ? w1 : skw;      // bot rows = rows 512+kr
    wts[e] = (kr < 4) ? (bf16_t)src2[(512 + kr) * 256 + n2] : (bf16_t)0.f;
    return;
  }
  int m = e >> 16;
  int r = e & 65535;
  int nt = r >> 12, kc = (r >> 9) & 7, lane = (r >> 3) & 63, j = r & 7;
  int n = (nt >> 1) * 32 + (lane & 15) * 2 + (nt & 1);
  int k = kc * 32 + (lane >> 4) * 8 + j;
  if (m == 10) {                               // compact final_w tile
    wts[e] = (n < 4) ? (bf16_t)fw[k * 4 + n] : (bf16_t)0.f;
    return;
  }
  const float* src;
  if      (m == 0) src = condw;
  else if (m == 1) src = w1;                    // blk0_w1 rows 0..255 (cond part)
  else if (m == 2) src = skw;                   // blk0_skip_w rows 0..255
  else if (m == 3) src = w2;                    // blk0_w2
  else if (m <= 6) src = bw1 + (m - 4) * 65536; // blks_w1[i]
  else             src = bw2 + (m - 7) * 65536; // blks_w2[i]
  wts[e] = (bf16_t)src[k * 256 + n];
}

// ---------------- kernel 2: per-step vectors + scalars ---------------------
__global__ void prep_kernel(const float* __restrict__ time_w,
                            const float* __restrict__ time_b,
                            const float* __restrict__ w1,
                            const float* __restrict__ b1,
                            const float* __restrict__ skw,
                            const float* __restrict__ skb,
                            float* __restrict__ tvecs,
                            float* __restrict__ stepsc) {
  int s = blockIdx.x;          // 0..9, t = 90 - 10*s
  int j = threadIdx.x;         // 0..255
  int t = 90 - s * 10;
  float tval = (float)t;
  __shared__ float emb[256];
  __shared__ float temb[256];
  if (j < 128) {
    float freq = expf((float)j * -0.07252236513366287f);  // -ln(1e4)/127
    float e = tval * freq;
    emb[j] = sinf(e);
    emb[j + 128] = cosf(e);
  }
  __syncthreads();
  float a = time_b[j];
  for (int k = 0; k < 256; ++k) a = fmaf(emb[k], time_w[k * 256 + j], a);
  temb[j] = gelu_f(a);
  __syncthreads();
  float v1 = b1[j], v2 = skb[j];
  for (int k = 0; k < 256; ++k) {
    float tk = temb[k];
    v1 = fmaf(tk, w1[(256 + k) * 256 + j], v1);    // blk0_w1 rows 256..511
    v2 = fmaf(tk, skw[(256 + k) * 256 + j], v2);   // blk0_skip_w rows 256..511
  }
  tvecs[s * 512 + j] = v1;         // tw1 (includes b1)
  tvecs[s * 512 + 256 + j] = v2;   // tskip (includes skip_b)
  if (j == 0) {
    float step = (0.02f - 1e-4f) / 99.0f;
    float acp = 1.0f, beta = 0.0f;
    for (int i = 0; i <= t; ++i) {
      beta = fmaf((float)i, step, 1e-4f);
      acp *= (1.0f - beta);
    }
    stepsc[s * 4 + 0] = 1.0f / sqrtf(1.0f - beta);   // 1/sqrt(alpha)
    stepsc[s * 4 + 1] = beta / sqrtf(1.0f - acp);    // b/sqrt(1-acp)
    stepsc[s * 4 + 2] = (t > 0) ? sqrtf(beta) : 0.0f;
    stepsc[s * 4 + 3] = 0.0f;
  }
}

// ---------------- kernel 3: x0 + noises via PARTITIONABLE threefry ---------
__global__ void noise_kernel(float* __restrict__ xout, float* __restrict__ nout, int nb) {
  int gid = blockIdx.x * 256 + threadIdx.x;
  int nx = nb * 4;     // 131072 x0 elements
  int nn = nb * 40;    // 1310720 noise elements
  uint32_t k0, k1, o0, o1;
  if (gid < nx) {
    tf2(0u, 42u, 0u, 999u, k0, k1);                 // fold_in(key(42), 999)
    tf2(k0, k1, 0u, (uint32_t)gid, o0, o1);
    xout[gid] = nrm_from_bits(o0 ^ o1);
  } else if (gid < nx + nn) {
    int i = gid - nx;
    tf2(0u, 42u, 0u, 7u, k0, k1);                   // fold_in(key(42), 7)
    tf2(k0, k1, 0u, (uint32_t)i, o0, o1);
    nout[i] = nrm_from_bits(o0 ^ o1);
  }
}

// ---------------- kernel 4: cond = features @ cond_w + cond_b --------------
__global__ __launch_bounds__(256, 2) void cond_kernel(
    const float* __restrict__ feat, const bf16_t* __restrict__ wts,
    const float* __restrict__ condb, bf16_t* __restrict__ condg) {
  __shared__ __align__(16) bf16_t la[MTILE * KP];
  const int tid = threadIdx.x;
  const int wave = tid >> 6, lane = tid & 63, quad = lane >> 4, l16 = lane & 15;
  const int rowbase = blockIdx.x * MTILE;
  for (int it = 0; it < 16; ++it) {
    int e = (it * 256 + tid) * 4;
    int rr = e >> 8, c = e & 255;
    f32x4 v = *(const f32x4*)(feat + (size_t)(rowbase + rr) * 256 + c);
    bf16x4 bv;
    bv[0] = (bf16_t)v[0]; bv[1] = (bf16_t)v[1];
    bv[2] = (bf16_t)v[2]; bv[3] = (bf16_t)v[3];
    *(bf16x4*)(la + rr * KP + c) = bv;
  }
  __syncthreads();
  f32x4 acc[16];
  mm_tile(la + l16 * KP + quad * 8, wts + wave * 16384 + lane * 8, acc);
  const int c0 = wave * 64 + l16 * 2;            // ct 0,1 -> c0, ct 2,3 -> c0+32
  f32x2 b0 = *(const f32x2*)(condb + c0);
  f32x2 b1 = *(const f32x2*)(condb + c0 + 32);
  #pragma unroll
  for (int rt = 0; rt < 4; ++rt)
    #pragma unroll
    for (int r = 0; r < 4; ++r) {
      int row = rt * 16 + quad * 4 + r;
      bf16x2 p0, p1;
      p0[0] = (bf16_t)(acc[rt * 4 + 0][r] + b0[0]);
      p0[1] = (bf16_t)(acc[rt * 4 + 1][r] + b0[1]);
      p1[0] = (bf16_t)(acc[rt * 4 + 2][r] + b1[0]);
      p1[1] = (bf16_t)(acc[rt * 4 + 3][r] + b1[1]);
      *(bf16x2*)(condg + (size_t)(rowbase + row) * 256 + c0) = p0;
      *(bf16x2*)(condg + (size_t)(rowbase + row) * 256 + c0 + 32) = p1;
    }
}

// ---------------- kernel 5: fused 10-step sampler (512 thr / 8 waves) ------
// r18 champion structure + pred software-pipelined under next-step dual-main.
__global__ __launch_bounds__(512, 1) void fused_kernel(
    const bf16_t* __restrict__ condg, const bf16_t* __restrict__ wts,
    const float* __restrict__ tvecs, const float* __restrict__ stepsc,
    const float* __restrict__ x0w, const float* __restrict__ noises,
    const float* __restrict__ b2v, const float* __restrict__ blksb1,
    const float* __restrict__ blksb2,
    const float* __restrict__ finalb, float* __restrict__ out, int nb) {
  __shared__ __align__(16) bf16_t lcond[MTILE * KP];
  __shared__ __align__(16) bf16_t lact0[MTILE * KP];   // double-buffered act
  __shared__ __align__(16) bf16_t lact1[MTILE * KP];
  __shared__ __align__(16) float  lx[MTILE * 4];
  __shared__ __align__(16) bf16_t lxb[MTILE * 32];     // x as bf16, K-extension A
  const int tid = threadIdx.x;
  const int wave = tid >> 6, lane = tid & 63, quad = lane >> 4, l16 = lane & 15;
  const int rowbase = blockIdx.x * MTILE;

  // stage cond tile (persists all 10 steps) + x0 (+ lxb init)
  {
    int rr = tid >> 3, c = (tid & 7) * 32;
    const bf16_t* src = condg + (size_t)(rowbase + rr) * 256 + c;
    bf16_t* dst = lcond + rr * KP + c;
    #pragma unroll
    for (int j = 0; j < 4; ++j)
      *(bf16x8*)(dst + j * 8) = *(const bf16x8*)(src + j * 8);
  }
  for (int i = tid; i < MTILE * 32; i += 512)
    if ((i & 31) >= 4) lxb[i] = (bf16_t)0.f;   // zero pad cols 4..31 (once)
  if (tid < 256) {
    float xv = x0w[rowbase * 4 + tid];
    lx[tid] = xv;
    lxb[(tid >> 2) * 32 + (tid & 3)] = (bf16_t)xv;
  }
  __syncthreads();

  const bf16_t* Acond = lcond + l16 * KP + quad * 8;
  const bf16_t* A0    = lact0 + l16 * KP + quad * 8;
  const bf16_t* A1    = lact1 + l16 * KP + quad * 8;
  const int colw = wave * 32 + l16 * 2;          // 2 consecutive cols/lane
  const int wlane = wave * 8192 + lane * 8;
  const bf16_t* BS = wts + WT_BS + wave * 1024 + lane * 8;  // skipbot frag
  const bf16_t* BW = wts + WT_BW + wave * 1024 + lane * 8;  // w1bot frag
  f32x4 resid[8], work[8];

  // step-invariant per-column constants, hoisted to registers
  const f32x2 b2c = *(const f32x2*)(b2v + colw);
  f32x2 g1c[3], g2c[3];
  #pragma unroll
  for (int blk = 0; blk < 3; ++blk) {
    g1c[blk] = *(const f32x2*)(blksb1 + blk * 256 + colw);
    g2c[blk] = *(const f32x2*)(blksb2 + blk * 256 + colw);
  }
  f32x2 fbc;
  {
    int bi = (l16 < 2) ? (int)(l16 * 2) : 0;   // valid lanes only; rest unused
    fbc[0] = finalb[bi]; fbc[1] = finalb[bi + 1];
  }

  // pack lane's 2 consecutive cols -> one ds_write_b32 per (rt,r)
  auto write_act = [&](bf16_t* dst) {
    #pragma unroll
    for (int rt = 0; rt < 4; ++rt)
      #pragma unroll
      for (int r = 0; r < 4; ++r) {
        bf16x2 pv;
        pv[0] = (bf16_t)work[rt * 2 + 0][r];
        pv[1] = (bf16_t)work[rt * 2 + 1][r];
        *(bf16x2*)(dst + (rt * 16 + quad * 4 + r) * KP + colw) = pv;
      }
  };
  auto epi_gelu = [&]() {        // bias already in acc init
    #pragma unroll
    for (int rt = 0; rt < 4; ++rt)
      #pragma unroll
      for (int r = 0; r < 4; ++r) {
        f32x2 v = gelu2(f32x2{work[rt * 2][r], work[rt * 2 + 1][r]});
        work[rt * 2][r] = v[0]; work[rt * 2 + 1][r] = v[1];
      }
  };
  auto epi_gelu_res = [&]() {    // bias already in acc init
    #pragma unroll
    for (int rt = 0; rt < 4; ++rt)
      #pragma unroll
      for (int r = 0; r < 4; ++r) {
        f32x2 v = gelu2(f32x2{work[rt * 2][r], work[rt * 2 + 1][r]})
                + f32x2{resid[rt * 2][r], resid[rt * 2 + 1][r]};
        resid[rt * 2][r] = v[0]; resid[rt * 2 + 1][r] = v[1];
        work[rt * 2][r] = v[0];  work[rt * 2 + 1][r] = v[1];
      }
  };
  // pred_{ps}: lact1 (= h_ps) @ final_w + final_b; x-update -> lx, lxb.
  // Runs on waves 0,1 only (32 rows each).
  auto do_pred = [&](int ps) {
    f32x4 pacc[4];
    mm_tile22(lact1 + (wave * 32 + l16) * KP + quad * 8,
              wts + WT_FW + lane * 8, pacc, fbc);      // + final_b folded
    if (l16 < 2) {
      f32x4 sc = *(const f32x4*)(stepsc + ps * 4);
      #pragma unroll
      for (int ct = 0; ct < 2; ++ct) {
        int col = l16 * 2 + ct;
        #pragma unroll
        for (int rt = 0; rt < 2; ++rt)
          #pragma unroll
          for (int r = 0; r < 4; ++r) {
            int row = wave * 32 + rt * 16 + quad * 4 + r;
            float accp = pacc[rt * 2 + ct][r];
            float xv = lx[row * 4 + col];
            xv = (xv - sc[1] * accp) * sc[0];
            xv = fmaf(sc[2],
                      noises[(size_t)ps * nb * 4 + (size_t)(rowbase + row) * 4 + col],
                      xv);
            lx[row * 4 + col] = xv;
            lxb[row * 32 + col] = (bf16_t)xv;
          }
      }
    }
  };

  for (int s = 0; s < 10; ++s) {
    const float* tw  = tvecs + s * 512;
    const float* tsk = tvecs + s * 512 + 256;
    f32x2 tcw = *(const f32x2*)(tw + colw);
    f32x2 tcs = *(const f32x2*)(tsk + colw);
    // (1) dual main: skip -> resid (C init tskip), y1 -> work (C init tw1).
    //     Reads ONLY lcond (static) -- x-independent.
    mm_dual_main(Acond, wts + 2 * 65536 + wlane, wts + 1 * 65536 + wlane,
                 resid, work, tcs, tcw);
    // (2) deferred pred for step s-1 on waves 0,1 (overlaps (1) on other
    //     waves' SIMD slots). lact1 still holds h_{s-1}; produces x_s.
    if (s > 0 && wave < 2) do_pred(s - 1);
    __syncthreads();                               // P: x_s in lx/lxb visible
    // (3) K-extension: x_s @ bot folded into both accs; then gelu y1.
    mm_dual_ext(lxb, BS, BW, l16, quad, resid, work);
    epi_gelu();
    write_act(lact0);
    __syncthreads();                               // B1: y1 in lact0
    // h = gelu(y1 @ W2 + b2) + skip                -> lact1
    mm_tile2(A0, wts + 3 * 65536 + wlane, work, b2c);
    epi_gelu_res();
    write_act(lact1);     // != read buffer: no pre-barrier needed
    __syncthreads();                               // B2: h in lact1
    // 3 residual blocks: g1 lact1->lact0, g2 lact0->lact1
    for (int blk = 0; blk < 3; ++blk) {
      mm_tile2(A1, wts + (4 + blk) * 65536 + wlane, work, g1c[blk]);
      epi_gelu();
      write_act(lact0);
      __syncthreads();                             // g1 in lact0
      mm_tile2(A0, wts + (7 + blk) * 65536 + wlane, work, g2c[blk]);
      epi_gelu_res();
      write_act(lact1);
      __syncthreads();                             // g2 in lact1
    }
    // (pred for THIS step deferred into next iteration / epilogue)
  }
  // epilogue: pred_9 + final x-update
  if (wave < 2) do_pred(9);
  __syncthreads();
  if (tid < 256) {
    float xf = lx[tid];
    xf = fminf(1.0f, fmaxf(-1.0f, xf));
    out[rowbase * 4 + tid] = xf;
  }
}

// ---------------------------------------------------------------------------
extern "C" void kernel_launch(void* const* d_in, const int* in_sizes, int n_in,
                              void* d_out, int out_size, void* d_ws, size_t ws_size,
                              hipStream_t stream) {
  (void)n_in; (void)out_size; (void)ws_size;
  const float* features    = (const float*)d_in[0];
  const float* cond_w      = (const float*)d_in[1];
  const float* cond_b      = (const float*)d_in[2];
  const float* time_w      = (const float*)d_in[3];
  const float* time_b      = (const float*)d_in[4];
  const float* blk0_w1     = (const float*)d_in[5];
  const float* blk0_b1     = (const float*)d_in[6];
  const float* blk0_w2     = (const float*)d_in[7];
  const float* blk0_b2     = (const float*)d_in[8];
  const float* blk0_skip_w = (const float*)d_in[9];
  const float* blk0_skip_b = (const float*)d_in[10];
  const float* blks_w1     = (const float*)d_in[11];
  const float* blks_b1     = (const float*)d_in[12];
  const float* blks_w2     = (const float*)d_in[13];
  const float* blks_b2     = (const float*)d_in[14];
  const float* final_w     = (const float*)d_in[15];
  const float* final_b     = (const float*)d_in[16];

  const int nb = in_sizes[0] / 256;   // batch (32768)

  // workspace layout (bytes, 256-aligned)
  char* ws = (char*)d_ws;
  bf16_t* wts    = (bf16_t*)(ws + 0);        // 679936 bf16 = 1,359,872 B
  float*  tvecs  = (float*)(ws + 1359872);   // 10 * 512 f32    = 20,480 B
  float*  stepsc = (float*)(ws + 1380352);   // 10 * 4 f32      (pad to 256)
  float*  x0w    = (float*)(ws + 1380608);   // nb*4 f32        = 524,288 B
  float*  noisew = (float*)(ws + 1904896);   // 10*nb*4 f32     = 5,242,880 B
  bf16_t* condw  = (bf16_t*)(ws + 7147776);  // nb*256 bf16     = 16,777,216 B

  wprep_kernel<<<(WT_TOT + 255) / 256, 256, 0, stream>>>(
      cond_w, blk0_w1, blk0_skip_w, blk0_w2, blks_w1, blks_w2, final_w, wts);
  prep_kernel<<<10, 256, 0, stream>>>(time_w, time_b, blk0_w1, blk0_b1,
                                      blk0_skip_w, blk0_skip_b, tvecs, stepsc);
  noise_kernel<<<(nb * 44 + 255) / 256, 256, 0, stream>>>(x0w, noisew, nb);
  cond_kernel<<<nb / MTILE, 256, 0, stream>>>(features, wts, cond_b, condw);
  fused_kernel<<<nb / MTILE, 512, 0, stream>>>(
      condw, wts, tvecs, stepsc, x0w, noisew,
      blk0_b2, blks_b1, blks_b2, final_b, (float*)d_out, nb);
}